// Round 6
// baseline (1273.445 us; speedup 1.0000x reference)
//
#include <hip/hip_runtime.h>
#include <hip/hip_fp16.h>
#include <cstdint>
#include <cstddef>

#define N_NODES_C  100000
#define N_EDGES_C  1600000
#define N_GRAPHS_C 256
#define HID_C      128
// 1/sqrt(1+1e-5)
#define BN_SCALE_C 0.9999950000374997f

#define SCAN_B 1024
#define SCAN_NB ((N_NODES_C + SCAN_B - 1) / SCAN_B)   // 98

typedef _Float16 h2 __attribute__((ext_vector_type(2)));
typedef _Float16 h4 __attribute__((ext_vector_type(4)));
typedef _Float16 h8 __attribute__((ext_vector_type(8)));
typedef float    f4 __attribute__((ext_vector_type(4)));

struct __align__(16) EA8 { h2 p[4]; };       // 8 fp16 = 16 B
struct __align__(8)  HQ  { h2 a, b; };       // 4 fp16 = 8 B
struct __align__(16) H8  { __half2 v[4]; };  // preamble convert

#if defined(__has_builtin)
#  if __has_builtin(__builtin_amdgcn_fdot2)
#    define HAVE_FDOT2 1
#  endif
#endif
#ifndef HAVE_FDOT2
#  define HAVE_FDOT2 0
#endif

__device__ __forceinline__ float fdot2_(h2 a, h2 b, float c)
{
#if HAVE_FDOT2
    return __builtin_amdgcn_fdot2(a, b, c, false);
#else
    return c + (float)a[0] * (float)b[0] + (float)a[1] * (float)b[1];
#endif
}

// ---------------------------------------------------------------------------
// CSR build: histogram of dst, inclusive scan, scatter edge ids.
// ---------------------------------------------------------------------------
__global__ __launch_bounds__(256) void hist_kernel(
    const int* __restrict__ dst, int* __restrict__ counts, int n_edges)
{
    int e = blockIdx.x * 256 + threadIdx.x;
    if (e < n_edges) atomicAdd(&counts[dst[e]], 1);
}

__global__ __launch_bounds__(SCAN_B) void scan1_kernel(
    const int* __restrict__ counts, int* __restrict__ incl,
    int* __restrict__ blocksums, int n)
{
    __shared__ int sdata[SCAN_B];
    const int lid = threadIdx.x;
    const int i = blockIdx.x * SCAN_B + lid;
    sdata[lid] = (i < n) ? counts[i] : 0;
    __syncthreads();
#pragma unroll
    for (int off = 1; off < SCAN_B; off <<= 1) {
        int t = (lid >= off) ? sdata[lid - off] : 0;
        __syncthreads();
        sdata[lid] += t;
        __syncthreads();
    }
    if (i < n) incl[i] = sdata[lid];
    if (lid == SCAN_B - 1) blocksums[blockIdx.x] = sdata[lid];
}

__global__ void scan2_kernel(const int* __restrict__ blocksums,
                             int* __restrict__ blockoffs, int nb)
{
    if (threadIdx.x == 0 && blockIdx.x == 0) {
        int off = 0;
        for (int b = 0; b < nb; ++b) { blockoffs[b] = off; off += blocksums[b]; }
    }
}

__global__ __launch_bounds__(SCAN_B) void scan3_kernel(
    int* __restrict__ incl, const int* __restrict__ blockoffs, int n)
{
    const int i = blockIdx.x * SCAN_B + threadIdx.x;
    if (i < n) incl[i] += blockoffs[blockIdx.x];
}

__global__ __launch_bounds__(256) void initrows_kernel(
    const int* __restrict__ incl, const int* __restrict__ counts,
    int* __restrict__ rowstart, int* __restrict__ cursor, int n)
{
    const int i = blockIdx.x * 256 + threadIdx.x;
    if (i < n) {
        const int rs = incl[i] - counts[i];
        rowstart[i] = rs;
        cursor[i]   = rs;
    }
}

// Two 4B random stores per edge; agg hot loop then reads only perm_src (4B).
__global__ __launch_bounds__(256) void scatter_kernel(
    const int* __restrict__ src, const int* __restrict__ dst,
    int* __restrict__ cursor, int* __restrict__ perm_src,
    int* __restrict__ perm_eid, int n_edges)
{
    const int e = blockIdx.x * 256 + threadIdx.x;
    if (e < n_edges) {
        const int pos = atomicAdd(&cursor[dst[e]], 1);
        perm_src[pos] = src[e];
        perm_eid[pos] = e;
    }
}

// Gather edge_attr rows into CSR order AND convert to fp16 pairs.
__global__ __launch_bounds__(256) void permute_ea_f16_kernel(
    const float* __restrict__ edge_attr, const int* __restrict__ perm_eid,
    __half* __restrict__ ea_f16, int n_edges)
{
    const int j = blockIdx.x * 256 + threadIdx.x;
    if (j >= n_edges) return;
    const int eid = perm_eid[j];
    const float4* p = (const float4*)(edge_attr + (size_t)eid * 16);
    const float4 q0 = p[0], q1 = p[1], q2 = p[2], q3 = p[3];
    H8 a, b;
    a.v[0] = __floats2half2_rn(q0.x, q0.y);
    a.v[1] = __floats2half2_rn(q0.z, q0.w);
    a.v[2] = __floats2half2_rn(q1.x, q1.y);
    a.v[3] = __floats2half2_rn(q1.z, q1.w);
    b.v[0] = __floats2half2_rn(q2.x, q2.y);
    b.v[1] = __floats2half2_rn(q2.z, q2.w);
    b.v[2] = __floats2half2_rn(q3.x, q3.y);
    b.v[3] = __floats2half2_rn(q3.z, q3.w);
    H8* o = (H8*)(ea_f16 + (size_t)j * 16);
    o[0] = a;
    o[1] = b;
}

// Cast fp32 array -> f16 (vectorized by 4).
__global__ __launch_bounds__(256) void cast_f16_kernel(
    const float* __restrict__ in, _Float16* __restrict__ out, int n4)
{
    const int i = blockIdx.x * 256 + threadIdx.x;
    if (i >= n4) return;
    const float4 v = ((const float4*)in)[i];
    h4 o; o[0] = (_Float16)v.x; o[1] = (_Float16)v.y;
    o[2] = (_Float16)v.z; o[3] = (_Float16)v.w;
    *(h4*)(out + (size_t)i * 4) = o;
}

// Transpose + cast weights: wt[n][k] = (f16) w[k][n].  (tiny, one-time)
__global__ __launch_bounds__(256) void transpose_w_kernel(
    const float* __restrict__ w, _Float16* __restrict__ wt, int K, int N)
{
    const int i = blockIdx.x * 256 + threadIdx.x;
    if (i >= K * N) return;
    const int n = i / K;
    const int k = i - n * K;
    wt[(size_t)n * K + k] = (_Float16)w[(size_t)k * N + n];
}

// Pack edge-MLP weights for the agg kernel: per output-quad fq, 32 h2
// values laid out contiguously (64 B = 4 dwordx4 loads in the prologue).
// out[fq*32 + k2*4 + fi] = ( ew[2k2][fq*4+fi], ew[2k2+1][fq*4+fi] )
__global__ __launch_bounds__(256) void pack_ew_kernel(
    const float* __restrict__ ew, h2* __restrict__ out, int din)
{
    const int i = blockIdx.x * 256 + threadIdx.x;
    const int total = din * 8;             // (din/4) * 32
    if (i >= total) return;
    const int fq = i >> 5, r = i & 31, k2 = r >> 2, fi = r & 3;
    const int f = fq * 4 + fi;
    h2 t;
    t[0] = (_Float16)ew[(size_t)(2 * k2)     * din + f];
    t[1] = (_Float16)ew[(size_t)(2 * k2 + 1) * din + f];
    out[i] = t;
}

// ---------------------------------------------------------------------------
// Edge MLP for one edge (lane's 4 output features) via fdot2.
// ---------------------------------------------------------------------------
__device__ __forceinline__ float4 eamlp2(const h8 a8, const h8 c8,
                                         const h2 (&ew2h)[8][4], const float4 ebv)
{
    h2 ap[4], cp[4];
#pragma unroll
    for (int k = 0; k < 4; ++k) {
        ap[k][0] = a8[2 * k]; ap[k][1] = a8[2 * k + 1];
        cp[k][0] = c8[2 * k]; cp[k][1] = c8[2 * k + 1];
    }
    float4 m = {ebv.x, ebv.y, ebv.z, ebv.w};
#pragma unroll
    for (int k = 0; k < 4; ++k) {
        m.x = fdot2_(ap[k], ew2h[k][0], m.x);
        m.y = fdot2_(ap[k], ew2h[k][1], m.y);
        m.z = fdot2_(ap[k], ew2h[k][2], m.z);
        m.w = fdot2_(ap[k], ew2h[k][3], m.w);
    }
#pragma unroll
    for (int k = 0; k < 4; ++k) {
        m.x = fdot2_(cp[k], ew2h[4 + k][0], m.x);
        m.y = fdot2_(cp[k], ew2h[4 + k][1], m.y);
        m.z = fdot2_(cp[k], ew2h[4 + k][2], m.z);
        m.w = fdot2_(cp[k], ew2h[4 + k][3], m.w);
    }
    return m;
}

// U edges: all U h-gathers issued first (long-latency, in flight together);
// ea16 stream (nontemporal, read-once) consumed per-edge to bound liveness.
template<int DIN, int U>
__device__ __forceinline__ void agg_edges(
    const _Float16* __restrict__ hin, const _Float16* __restrict__ ea16,
    const int* __restrict__ perm_src, int j, int fq,
    const h2 (&ew2h)[8][4], const float4 ebv, float4& acc)
{
    int sn[U];
#pragma unroll
    for (int u = 0; u < U; ++u) sn[u] = perm_src[j + u];
    HQ hq[U];
#pragma unroll
    for (int u = 0; u < U; ++u)
        hq[u] = *(const HQ*)(hin + (size_t)sn[u] * DIN + fq * 4);
#pragma unroll
    for (int u = 0; u < U; ++u) {
        const h8* pe = (const h8*)(ea16 + (size_t)(j + u) * 16);
        const h8 a = __builtin_nontemporal_load(pe);
        const h8 c = __builtin_nontemporal_load(pe + 1);
        const float4 m = eamlp2(a, c, ew2h, ebv);
        acc.x += fmaxf(m.x + (float)hq[u].a[0], 0.f);
        acc.y += fmaxf(m.y + (float)hq[u].a[1], 0.f);
        acc.z += fmaxf(m.z + (float)hq[u].b[0], 0.f);
        acc.w += fmaxf(m.w + (float)hq[u].b[1], 0.f);
    }
}

// ---------------------------------------------------------------------------
// CSR aggregate (high-TLP: one node per 32/16-lane slot, no barriers).
// ILP-8 main loop (8 independent gathers in flight), 4/2/1 tails.
// Prologue: packed-f16 edge weights via 4 vector loads (pack_ew_kernel).
// Adds residual h_v and writes x16 = h+agg as f16.
// ---------------------------------------------------------------------------
template<int DIN>
__global__ __launch_bounds__(256) void gine_agg_kernel(
    const _Float16* __restrict__ hin, const _Float16* __restrict__ ea16,
    const int* __restrict__ perm_src,
    const int* __restrict__ rowstart, const int* __restrict__ rowend,
    const h2* __restrict__ ew16, const float* __restrict__ eb,
    _Float16* __restrict__ x16, int n_nodes)
{
    constexpr int NQ    = DIN / 4;
    constexpr int SLOTS = 256 / NQ;
    const int fq   = threadIdx.x & (NQ - 1);
    const int slot = threadIdx.x / NQ;
    const int v = blockIdx.x * SLOTS + slot;
    if (v >= n_nodes) return;

    // packed f16 edge weights: 4 x 16B loads, statically unpacked to regs
    h8 w0 = *(const h8*)(ew16 + (size_t)fq * 32);
    h8 w1 = *(const h8*)(ew16 + (size_t)fq * 32 + 4);
    h8 w2 = *(const h8*)(ew16 + (size_t)fq * 32 + 8);
    h8 w3 = *(const h8*)(ew16 + (size_t)fq * 32 + 12);
    h2 ew2h[8][4];
#pragma unroll
    for (int r = 0; r < 4; ++r) {
        const h8 wv = (r == 0) ? w0 : (r == 1) ? w1 : (r == 2) ? w2 : w3;
#pragma unroll
        for (int c = 0; c < 4; ++c) {
            h2 t; t[0] = wv[2 * c]; t[1] = wv[2 * c + 1];
            ew2h[r * 2 + (c >> 1)][(c & 1) * 2 + 0] = t;   // placeholder, fixed below
        }
    }
    // direct unpack (ew16 layout: [k2=0..7][fi=0..3] h2 values, 32 h2 total)
    {
        const h2* wl = (const h2*)(ew16 + (size_t)fq * 32);
#pragma unroll
        for (int k2 = 0; k2 < 8; ++k2)
#pragma unroll
            for (int fi = 0; fi < 4; ++fi)
                ew2h[k2][fi] = wl[k2 * 4 + fi];
    }
    const float4 ebv = *(const float4*)(eb + fq * 4);

    const int s0 = rowstart[v];
    const int s1 = rowend[v];

    // residual row (own node): issue early, independent of the loop
    const HQ hv = *(const HQ*)(hin + (size_t)v * DIN + fq * 4);

    float4 acc = {0.f, 0.f, 0.f, 0.f};
    int j = s0;
    for (; j + 8 <= s1; j += 8)
        agg_edges<DIN, 8>(hin, ea16, perm_src, j, fq, ew2h, ebv, acc);
    if (j + 4 <= s1) {
        agg_edges<DIN, 4>(hin, ea16, perm_src, j, fq, ew2h, ebv, acc);
        j += 4;
    }
    if (j + 2 <= s1) {
        agg_edges<DIN, 2>(hin, ea16, perm_src, j, fq, ew2h, ebv, acc);
        j += 2;
    }
    if (j < s1)
        agg_edges<DIN, 1>(hin, ea16, perm_src, j, fq, ew2h, ebv, acc);

    // residual + f16 store: x = h_v + agg
    h4 o;
    o[0] = (_Float16)(acc.x + (float)hv.a[0]);
    o[1] = (_Float16)(acc.y + (float)hv.a[1]);
    o[2] = (_Float16)(acc.z + (float)hv.b[0]);
    o[3] = (_Float16)(acc.w + (float)hv.b[1]);
    *(h4*)(x16 + (size_t)v * DIN + fq * 4) = o;
}

// ---------------------------------------------------------------------------
// Node MLP: 4 waves per block, 1 tile (16 nodes) per wave. A-fragments for
// mm1 read DIRECTLY from global x16 (f16) -- no s_x staging. s_t LDS only
// for the mm1->mm2 transpose. Writes f16 h (next layer) or f32 h (pool).
// ---------------------------------------------------------------------------
template<int DIN, bool LASTL>
__global__ __launch_bounds__(256) void node_mfma_kernel(
    const _Float16* __restrict__ x16,
    const _Float16* __restrict__ w1t, const float* __restrict__ b1,
    const float* __restrict__ gm, const float* __restrict__ bt,
    const _Float16* __restrict__ w2t, const float* __restrict__ b2,
    float* __restrict__ hout, _Float16* __restrict__ h16out, int n_tiles)
{
    constexpr int STP = HID_C + 8;
    __shared__ _Float16 s_t[4][16][STP];

    const int w    = threadIdx.x >> 6;
    const int lane = threadIdx.x & 63;
    int tile = blockIdx.x * 4 + w;
    if (tile >= n_tiles) tile = n_tiles - 1;   // clamp: keep barriers uniform
    const int node0 = tile * 16;
    const int ln   = lane & 15;
    const int quad = lane >> 4;

    // preload A-fragments of X (row ln, cols quad*8 + ks*32) from global
    constexpr int NKS = DIN / 32;
    h8 af[NKS];
#pragma unroll
    for (int ks = 0; ks < NKS; ++ks)
        af[ks] = *(const h8*)(x16 + (size_t)(node0 + ln) * DIN + ks * 32 + quad * 8);

    // ---- mm1 + BN + relu -> s_t (f16) ----
#pragma unroll
    for (int nt = 0; nt < 8; ++nt) {
        const int col = nt * 16 + ln;
        const float bv = b1[col];
        f4 acc = {bv, bv, bv, bv};
#pragma unroll
        for (int ks = 0; ks < NKS; ++ks) {
            const h8 bf = *(const h8*)(w1t + (size_t)col * DIN + ks * 32 + quad * 8);
            acc = __builtin_amdgcn_mfma_f32_16x16x32_f16(af[ks], bf, acc, 0, 0, 0);
        }
        const float gv = gm[col], btv = bt[col];
#pragma unroll
        for (int r = 0; r < 4; ++r) {
            const float t = fmaxf(fmaf(acc[r] * BN_SCALE_C, gv, btv), 0.f);
            s_t[w][quad * 4 + r][col] = (_Float16)t;
        }
    }
    __syncthreads();

    // preload A-fragments of T
    h8 af2[4];
#pragma unroll
    for (int ks = 0; ks < 4; ++ks)
        af2[ks] = *(const h8*)&s_t[w][ln][ks * 32 + quad * 8];

    // ---- mm2 + relu -> h16 (or f32 h on last layer) ----
#pragma unroll
    for (int nt = 0; nt < 8; ++nt) {
        const int col = nt * 16 + ln;
        const float bv = b2[col];
        f4 acc = {bv, bv, bv, bv};
#pragma unroll
        for (int ks = 0; ks < 4; ++ks) {
            const h8 bf = *(const h8*)(w2t + (size_t)col * HID_C + ks * 32 + quad * 8);
            acc = __builtin_amdgcn_mfma_f32_16x16x32_f16(af2[ks], bf, acc, 0, 0, 0);
        }
#pragma unroll
        for (int r = 0; r < 4; ++r) {
            const int node = node0 + quad * 4 + r;
            const float v = fmaxf(acc[r], 0.f);
            if (LASTL) {
                hout[(size_t)node * HID_C + col] = v;
            } else {
                h16out[(size_t)node * HID_C + col] = (_Float16)v;
            }
        }
    }
}

// ---------------------------------------------------------------------------
// Pool + output MLP (unchanged).
// ---------------------------------------------------------------------------
__global__ __launch_bounds__(256) void pool_kernel(
    const float* __restrict__ hfin, const int* __restrict__ batch,
    const float* __restrict__ w1, const float* __restrict__ b1,
    const float* __restrict__ w2, const float* __restrict__ b2,
    float* __restrict__ out, int n_nodes)
{
    const int gid = blockIdx.x;

    int lo = 0, hi = n_nodes;
    while (lo < hi) { int mid = (lo + hi) >> 1; if (batch[mid] < gid) lo = mid + 1; else hi = mid; }
    const int start = lo;
    hi = n_nodes;
    while (lo < hi) { int mid = (lo + hi) >> 1; if (batch[mid] < gid + 1) lo = mid + 1; else hi = mid; }
    const int end = lo;

    const int f = threadIdx.x & (HID_C - 1);
    const int half = threadIdx.x >> 7;

    float sum = 0.f;
    for (int n = start + half; n < end; n += 2)
        sum += hfin[(size_t)n * HID_C + f];

    __shared__ float s_sum[2][HID_C];
    __shared__ float s_p[HID_C];
    __shared__ float s_t[HID_C];
    s_sum[half][f] = sum;
    __syncthreads();

    if (threadIdx.x < HID_C) {
        const float cnt = (float)(end - start);
        s_p[f] = (s_sum[0][f] + s_sum[1][f]) / fmaxf(cnt, 1.f);
    }
    __syncthreads();

    if (threadIdx.x < HID_C) {
        float acc = b1[f];
        for (int k = 0; k < HID_C; ++k) acc = fmaf(s_p[k], w1[k * HID_C + f], acc);
        s_t[f] = fmaxf(acc, 0.f);
    }
    __syncthreads();

    if (threadIdx.x < HID_C) {
        float acc = b2[f];
        for (int k = 0; k < HID_C; ++k) acc = fmaf(s_t[k], w2[k * HID_C + f], acc);
        out[(size_t)gid * HID_C + f] = acc;
    }
}

// ---------------------------------------------------------------------------
extern "C" void kernel_launch(void* const* d_in, const int* in_sizes, int n_in,
                              void* d_out, int out_size, void* d_ws, size_t ws_size,
                              hipStream_t stream)
{
    const float* x         = (const float*)d_in[0];
    const float* edge_attr = (const float*)d_in[1];
    const int*   edge_index= (const int*)  d_in[2];
    const int*   batch     = (const int*)  d_in[3];
    const int*   src = edge_index;
    const int*   dst = edge_index + N_EDGES_C;

    const float* el_w[3] = {(const float*)d_in[4],  (const float*)d_in[12], (const float*)d_in[20]};
    const float* el_b[3] = {(const float*)d_in[5],  (const float*)d_in[13], (const float*)d_in[21]};
    const float* c_w1[3] = {(const float*)d_in[6],  (const float*)d_in[14], (const float*)d_in[22]};
    const float* c_b1[3] = {(const float*)d_in[7],  (const float*)d_in[15], (const float*)d_in[23]};
    const float* c_g [3] = {(const float*)d_in[8],  (const float*)d_in[16], (const float*)d_in[24]};
    const float* c_bt[3] = {(const float*)d_in[9],  (const float*)d_in[17], (const float*)d_in[25]};
    const float* c_w2[3] = {(const float*)d_in[10], (const float*)d_in[18], (const float*)d_in[26]};
    const float* c_b2[3] = {(const float*)d_in[11], (const float*)d_in[19], (const float*)d_in[27]};
    const float* o_w1 = (const float*)d_in[28];
    const float* o_b1 = (const float*)d_in[29];
    const float* o_w2 = (const float*)d_in[30];
    const float* o_b2 = (const float*)d_in[31];

    // ---- workspace layout (~200 MB) ----
    char* wsp = (char*)d_ws;
    size_t used = 0;
    auto alloc = [&](size_t bytes) { char* p = wsp + used; used += (bytes + 255) & ~(size_t)255; return p; };
    float* h        = (float*)alloc((size_t)N_NODES_C * HID_C * 4);   // final f32 (pool input)
    int*   counts   = (int*)alloc((size_t)N_NODES_C * 4);
    int*   incl     = (int*)alloc((size_t)N_NODES_C * 4);
    int*   rowstart = (int*)alloc((size_t)N_NODES_C * 4);
    int*   cursor   = (int*)alloc((size_t)N_NODES_C * 4);
    int*   blocksums= (int*)alloc(128 * 4);
    int*   blockoffs= (int*)alloc(128 * 4);
    int*   perm_src = (int*)alloc((size_t)N_EDGES_C * 4);
    int*   perm_eid = (int*)alloc((size_t)N_EDGES_C * 4);
    _Float16* ea_f16 = (_Float16*)alloc((size_t)N_EDGES_C * 16 * 2);
    _Float16* x16    = (_Float16*)alloc((size_t)N_NODES_C * HID_C * 2);
    _Float16* h16_a  = (_Float16*)alloc((size_t)N_NODES_C * HID_C * 2);
    _Float16* h16_b  = (_Float16*)alloc((size_t)N_NODES_C * HID_C * 2);
    _Float16* x_f16  = (_Float16*)alloc((size_t)N_NODES_C * 64 * 2);
    _Float16* w1t[3], *w2t[3];
    h2* ew16p[3];
    for (int l = 0; l < 3; ++l) {
        w1t[l] = (_Float16*)alloc((size_t)HID_C * HID_C * 2);
        w2t[l] = (_Float16*)alloc((size_t)HID_C * HID_C * 2);
        ew16p[l] = (h2*)alloc((size_t)HID_C * 8 * 4);   // DIN*8 h2, DIN<=128
    }
    (void)ws_size;

    // ---- CSR build (once; reused by all 3 layers) ----
    hipMemsetAsync(counts, 0, (size_t)N_NODES_C * 4, stream);
    hist_kernel<<<(N_EDGES_C + 255) / 256, 256, 0, stream>>>(dst, counts, N_EDGES_C);
    scan1_kernel<<<SCAN_NB, SCAN_B, 0, stream>>>(counts, incl, blocksums, N_NODES_C);
    scan2_kernel<<<1, 64, 0, stream>>>(blocksums, blockoffs, SCAN_NB);
    scan3_kernel<<<SCAN_NB, SCAN_B, 0, stream>>>(incl, blockoffs, N_NODES_C);
    initrows_kernel<<<(N_NODES_C + 255) / 256, 256, 0, stream>>>(incl, counts, rowstart,
                                                                 cursor, N_NODES_C);
    scatter_kernel<<<(N_EDGES_C + 255) / 256, 256, 0, stream>>>(src, dst, cursor,
                                                                perm_src, perm_eid, N_EDGES_C);
    permute_ea_f16_kernel<<<(N_EDGES_C + 255) / 256, 256, 0, stream>>>(
        edge_attr, perm_eid, (__half*)ea_f16, N_EDGES_C);
    cast_f16_kernel<<<(N_NODES_C * 64 / 4 + 255) / 256, 256, 0, stream>>>(
        x, x_f16, N_NODES_C * 64 / 4);
    for (int l = 0; l < 3; ++l) {
        const int K1 = (l == 0) ? 64 : HID_C;
        transpose_w_kernel<<<(K1 * HID_C + 255) / 256, 256, 0, stream>>>(
            c_w1[l], w1t[l], K1, HID_C);
        transpose_w_kernel<<<(HID_C * HID_C + 255) / 256, 256, 0, stream>>>(
            c_w2[l], w2t[l], HID_C, HID_C);
        const int din = (l == 0) ? 64 : HID_C;
        pack_ew_kernel<<<(din * 8 + 255) / 256, 256, 0, stream>>>(
            el_w[l], ew16p[l], din);
    }

    const int n_tiles = N_NODES_C / 16;            // 6250
    const int nb_node = (n_tiles + 3) / 4;         // 1563

    // ---- 3 GINE layers (split: high-TLP agg -> MFMA node MLP) ----
    // layer 0 (DIN=64)
    gine_agg_kernel<64><<<(N_NODES_C + 15) / 16, 256, 0, stream>>>(
        x_f16, ea_f16, perm_src, rowstart, incl, ew16p[0], el_b[0],
        x16, N_NODES_C);
    node_mfma_kernel<64, false><<<nb_node, 256, 0, stream>>>(
        x16, w1t[0], c_b1[0], c_g[0], c_bt[0], w2t[0], c_b2[0],
        h, h16_a, n_tiles);
    // layer 1
    gine_agg_kernel<128><<<(N_NODES_C + 7) / 8, 256, 0, stream>>>(
        h16_a, ea_f16, perm_src, rowstart, incl, ew16p[1], el_b[1],
        x16, N_NODES_C);
    node_mfma_kernel<128, false><<<nb_node, 256, 0, stream>>>(
        x16, w1t[1], c_b1[1], c_g[1], c_bt[1], w2t[1], c_b2[1],
        h, h16_b, n_tiles);
    // layer 2
    gine_agg_kernel<128><<<(N_NODES_C + 7) / 8, 256, 0, stream>>>(
        h16_b, ea_f16, perm_src, rowstart, incl, ew16p[2], el_b[2],
        x16, N_NODES_C);
    node_mfma_kernel<128, true><<<nb_node, 256, 0, stream>>>(
        x16, w1t[2], c_b1[2], c_g[2], c_bt[2], w2t[2], c_b2[2],
        h, h16_a, n_tiles);

    // ---- pool + output MLP ----
    pool_kernel<<<N_GRAPHS_C, 256, 0, stream>>>(h, batch, o_w1, o_b1, o_w2, o_b2,
                                                (float*)d_out, N_NODES_C);
}

// Round 7
// 1183.756 us; speedup vs baseline: 1.0758x; 1.0758x over previous
//
#include <hip/hip_runtime.h>
#include <hip/hip_fp16.h>
#include <cstdint>
#include <cstddef>

#define N_NODES_C  100000
#define N_EDGES_C  1600000
#define N_GRAPHS_C 256
#define HID_C      128
// 1/sqrt(1+1e-5)
#define BN_SCALE_C 0.9999950000374997f

#define SCAN_B 1024
#define SCAN_NB ((N_NODES_C + SCAN_B - 1) / SCAN_B)   // 98

typedef _Float16 h2 __attribute__((ext_vector_type(2)));
typedef _Float16 h4 __attribute__((ext_vector_type(4)));
typedef _Float16 h8 __attribute__((ext_vector_type(8)));
typedef float    f4 __attribute__((ext_vector_type(4)));

struct __align__(16) EA8 { h2 p[4]; };       // 8 fp16 = 16 B
struct __align__(8)  HQ  { h2 a, b; };       // 4 fp16 = 8 B
struct __align__(16) H8  { __half2 v[4]; };  // preamble convert

#if defined(__has_builtin)
#  if __has_builtin(__builtin_amdgcn_fdot2)
#    define HAVE_FDOT2 1
#  endif
#endif
#ifndef HAVE_FDOT2
#  define HAVE_FDOT2 0
#endif

__device__ __forceinline__ float fdot2_(h2 a, h2 b, float c)
{
#if HAVE_FDOT2
    return __builtin_amdgcn_fdot2(a, b, c, false);
#else
    return c + (float)a[0] * (float)b[0] + (float)a[1] * (float)b[1];
#endif
}

// ---------------------------------------------------------------------------
// CSR build: histogram of dst, inclusive scan, scatter edge ids.
// ---------------------------------------------------------------------------
__global__ __launch_bounds__(256) void hist_kernel(
    const int* __restrict__ dst, int* __restrict__ counts, int n_edges)
{
    int e = blockIdx.x * 256 + threadIdx.x;
    if (e < n_edges) atomicAdd(&counts[dst[e]], 1);
}

__global__ __launch_bounds__(SCAN_B) void scan1_kernel(
    const int* __restrict__ counts, int* __restrict__ incl,
    int* __restrict__ blocksums, int n)
{
    __shared__ int sdata[SCAN_B];
    const int lid = threadIdx.x;
    const int i = blockIdx.x * SCAN_B + lid;
    sdata[lid] = (i < n) ? counts[i] : 0;
    __syncthreads();
#pragma unroll
    for (int off = 1; off < SCAN_B; off <<= 1) {
        int t = (lid >= off) ? sdata[lid - off] : 0;
        __syncthreads();
        sdata[lid] += t;
        __syncthreads();
    }
    if (i < n) incl[i] = sdata[lid];
    if (lid == SCAN_B - 1) blocksums[blockIdx.x] = sdata[lid];
}

__global__ void scan2_kernel(const int* __restrict__ blocksums,
                             int* __restrict__ blockoffs, int nb)
{
    if (threadIdx.x == 0 && blockIdx.x == 0) {
        int off = 0;
        for (int b = 0; b < nb; ++b) { blockoffs[b] = off; off += blocksums[b]; }
    }
}

__global__ __launch_bounds__(SCAN_B) void scan3_kernel(
    int* __restrict__ incl, const int* __restrict__ blockoffs, int n)
{
    const int i = blockIdx.x * SCAN_B + threadIdx.x;
    if (i < n) incl[i] += blockoffs[blockIdx.x];
}

__global__ __launch_bounds__(256) void initrows_kernel(
    const int* __restrict__ incl, const int* __restrict__ counts,
    int* __restrict__ rowstart, int* __restrict__ cursor, int n)
{
    const int i = blockIdx.x * 256 + threadIdx.x;
    if (i < n) {
        const int rs = incl[i] - counts[i];
        rowstart[i] = rs;
        cursor[i]   = rs;
    }
}

// Two 4B random stores per edge; agg hot loop then reads only perm_src (4B).
__global__ __launch_bounds__(256) void scatter_kernel(
    const int* __restrict__ src, const int* __restrict__ dst,
    int* __restrict__ cursor, int* __restrict__ perm_src,
    int* __restrict__ perm_eid, int n_edges)
{
    const int e = blockIdx.x * 256 + threadIdx.x;
    if (e < n_edges) {
        const int pos = atomicAdd(&cursor[dst[e]], 1);
        perm_src[pos] = src[e];
        perm_eid[pos] = e;
    }
}

// Gather edge_attr rows into CSR order AND convert to fp16 pairs.
__global__ __launch_bounds__(256) void permute_ea_f16_kernel(
    const float* __restrict__ edge_attr, const int* __restrict__ perm_eid,
    __half* __restrict__ ea_f16, int n_edges)
{
    const int j = blockIdx.x * 256 + threadIdx.x;
    if (j >= n_edges) return;
    const int eid = perm_eid[j];
    const float4* p = (const float4*)(edge_attr + (size_t)eid * 16);
    const float4 q0 = p[0], q1 = p[1], q2 = p[2], q3 = p[3];
    H8 a, b;
    a.v[0] = __floats2half2_rn(q0.x, q0.y);
    a.v[1] = __floats2half2_rn(q0.z, q0.w);
    a.v[2] = __floats2half2_rn(q1.x, q1.y);
    a.v[3] = __floats2half2_rn(q1.z, q1.w);
    b.v[0] = __floats2half2_rn(q2.x, q2.y);
    b.v[1] = __floats2half2_rn(q2.z, q2.w);
    b.v[2] = __floats2half2_rn(q3.x, q3.y);
    b.v[3] = __floats2half2_rn(q3.z, q3.w);
    H8* o = (H8*)(ea_f16 + (size_t)j * 16);
    o[0] = a;
    o[1] = b;
}

// Cast fp32 array -> f16 (vectorized by 4).
__global__ __launch_bounds__(256) void cast_f16_kernel(
    const float* __restrict__ in, _Float16* __restrict__ out, int n4)
{
    const int i = blockIdx.x * 256 + threadIdx.x;
    if (i >= n4) return;
    const float4 v = ((const float4*)in)[i];
    h4 o; o[0] = (_Float16)v.x; o[1] = (_Float16)v.y;
    o[2] = (_Float16)v.z; o[3] = (_Float16)v.w;
    *(h4*)(out + (size_t)i * 4) = o;
}

// Transpose + cast weights: wt[n][k] = (f16) w[k][n].  (tiny, one-time)
__global__ __launch_bounds__(256) void transpose_w_kernel(
    const float* __restrict__ w, _Float16* __restrict__ wt, int K, int N)
{
    const int i = blockIdx.x * 256 + threadIdx.x;
    if (i >= K * N) return;
    const int n = i / K;
    const int k = i - n * K;
    wt[(size_t)n * K + k] = (_Float16)w[(size_t)k * N + n];
}

// Pack edge-MLP weights for the agg kernel: per output-quad fq, 32 h2
// values laid out contiguously (128 B, vector-loadable in the prologue).
// out[fq*32 + k2*4 + fi] = ( ew[2k2][fq*4+fi], ew[2k2+1][fq*4+fi] )
__global__ __launch_bounds__(256) void pack_ew_kernel(
    const float* __restrict__ ew, h2* __restrict__ out, int din)
{
    const int i = blockIdx.x * 256 + threadIdx.x;
    const int total = din * 8;             // (din/4) * 32
    if (i >= total) return;
    const int fq = i >> 5, r = i & 31, k2 = r >> 2, fi = r & 3;
    const int f = fq * 4 + fi;
    h2 t;
    t[0] = (_Float16)ew[(size_t)(2 * k2)     * din + f];
    t[1] = (_Float16)ew[(size_t)(2 * k2 + 1) * din + f];
    out[i] = t;
}

// ---------------------------------------------------------------------------
// Edge MLP for one edge (lane's 4 output features) via fdot2.
// ---------------------------------------------------------------------------
__device__ __forceinline__ float4 eamlp2(const EA8 a0, const EA8 c0,
                                         const h2 (&ew2h)[8][4], const float4 ebv)
{
    float4 m = {ebv.x, ebv.y, ebv.z, ebv.w};
#pragma unroll
    for (int k = 0; k < 4; ++k) {
        m.x = fdot2_(a0.p[k], ew2h[k][0], m.x);
        m.y = fdot2_(a0.p[k], ew2h[k][1], m.y);
        m.z = fdot2_(a0.p[k], ew2h[k][2], m.z);
        m.w = fdot2_(a0.p[k], ew2h[k][3], m.w);
    }
#pragma unroll
    for (int k = 0; k < 4; ++k) {
        m.x = fdot2_(c0.p[k], ew2h[4 + k][0], m.x);
        m.y = fdot2_(c0.p[k], ew2h[4 + k][1], m.y);
        m.z = fdot2_(c0.p[k], ew2h[4 + k][2], m.z);
        m.w = fdot2_(c0.p[k], ew2h[4 + k][3], m.w);
    }
    return m;
}

// U edges: all U h-gathers issued first (long-latency, in flight together);
// ea16 stream (cached: neighbor slots share lines in L2) consumed per-edge.
template<int DIN, int U>
__device__ __forceinline__ void agg_edges(
    const _Float16* __restrict__ hin, const _Float16* __restrict__ ea16,
    const int* __restrict__ perm_src, int j, int fq,
    const h2 (&ew2h)[8][4], const float4 ebv, float4& acc)
{
    int sn[U];
#pragma unroll
    for (int u = 0; u < U; ++u) sn[u] = perm_src[j + u];
    HQ hq[U];
#pragma unroll
    for (int u = 0; u < U; ++u)
        hq[u] = *(const HQ*)(hin + (size_t)sn[u] * DIN + fq * 4);
#pragma unroll
    for (int u = 0; u < U; ++u) {
        const EA8* pe = (const EA8*)(ea16 + (size_t)(j + u) * 16);
        const EA8 a = pe[0], c = pe[1];
        const float4 m = eamlp2(a, c, ew2h, ebv);
        acc.x += fmaxf(m.x + (float)hq[u].a[0], 0.f);
        acc.y += fmaxf(m.y + (float)hq[u].a[1], 0.f);
        acc.z += fmaxf(m.z + (float)hq[u].b[0], 0.f);
        acc.w += fmaxf(m.w + (float)hq[u].b[1], 0.f);
    }
}

// ---------------------------------------------------------------------------
// CSR aggregate (high-TLP: one node per 32/16-lane slot, no barriers).
// ILP-8 main loop (8 independent gathers in flight), 4/2/1 tails.
// Prologue: packed-f16 edge weights (contiguous 128B, compiler-merged loads).
// Adds residual h_v and writes x16 = h+agg as f16.
// ---------------------------------------------------------------------------
template<int DIN>
__global__ __launch_bounds__(256) void gine_agg_kernel(
    const _Float16* __restrict__ hin, const _Float16* __restrict__ ea16,
    const int* __restrict__ perm_src,
    const int* __restrict__ rowstart, const int* __restrict__ rowend,
    const h2* __restrict__ ew16, const float* __restrict__ eb,
    _Float16* __restrict__ x16, int n_nodes)
{
    constexpr int NQ    = DIN / 4;
    constexpr int SLOTS = 256 / NQ;
    const int fq   = threadIdx.x & (NQ - 1);
    const int slot = threadIdx.x / NQ;
    const int v = blockIdx.x * SLOTS + slot;
    if (v >= n_nodes) return;

    // packed f16 edge weights: contiguous 128 B -> compiler merges to
    // dwordx4 loads; statically unpacked into ew2h regs.
    h2 ew2h[8][4];
    {
        const h2* wl = ew16 + (size_t)fq * 32;
#pragma unroll
        for (int k2 = 0; k2 < 8; ++k2)
#pragma unroll
            for (int fi = 0; fi < 4; ++fi)
                ew2h[k2][fi] = wl[k2 * 4 + fi];
    }
    const float4 ebv = *(const float4*)(eb + fq * 4);

    const int s0 = rowstart[v];
    const int s1 = rowend[v];

    // residual row (own node): issue early, independent of the loop
    const HQ hv = *(const HQ*)(hin + (size_t)v * DIN + fq * 4);

    float4 acc = {0.f, 0.f, 0.f, 0.f};
    int j = s0;
    for (; j + 8 <= s1; j += 8)
        agg_edges<DIN, 8>(hin, ea16, perm_src, j, fq, ew2h, ebv, acc);
    if (j + 4 <= s1) {
        agg_edges<DIN, 4>(hin, ea16, perm_src, j, fq, ew2h, ebv, acc);
        j += 4;
    }
    if (j + 2 <= s1) {
        agg_edges<DIN, 2>(hin, ea16, perm_src, j, fq, ew2h, ebv, acc);
        j += 2;
    }
    if (j < s1)
        agg_edges<DIN, 1>(hin, ea16, perm_src, j, fq, ew2h, ebv, acc);

    // residual + f16 store: x = h_v + agg
    h4 o;
    o[0] = (_Float16)(acc.x + (float)hv.a[0]);
    o[1] = (_Float16)(acc.y + (float)hv.a[1]);
    o[2] = (_Float16)(acc.z + (float)hv.b[0]);
    o[3] = (_Float16)(acc.w + (float)hv.b[1]);
    *(h4*)(x16 + (size_t)v * DIN + fq * 4) = o;
}

// ---------------------------------------------------------------------------
// Node MLP: 4 waves per block, 1 tile (16 nodes) per wave. A-fragments for
// mm1 read DIRECTLY from global x16 (f16) -- no s_x staging. s_t LDS only
// for the mm1->mm2 transpose. Writes f16 h (next layer) or f32 h (pool).
// ---------------------------------------------------------------------------
template<int DIN, bool LASTL>
__global__ __launch_bounds__(256) void node_mfma_kernel(
    const _Float16* __restrict__ x16,
    const _Float16* __restrict__ w1t, const float* __restrict__ b1,
    const float* __restrict__ gm, const float* __restrict__ bt,
    const _Float16* __restrict__ w2t, const float* __restrict__ b2,
    float* __restrict__ hout, _Float16* __restrict__ h16out, int n_tiles)
{
    constexpr int STP = HID_C + 8;
    __shared__ _Float16 s_t[4][16][STP];

    const int w    = threadIdx.x >> 6;
    const int lane = threadIdx.x & 63;
    int tile = blockIdx.x * 4 + w;
    if (tile >= n_tiles) tile = n_tiles - 1;   // clamp: keep barriers uniform
    const int node0 = tile * 16;
    const int ln   = lane & 15;
    const int quad = lane >> 4;

    // preload A-fragments of X (row ln, cols quad*8 + ks*32) from global
    constexpr int NKS = DIN / 32;
    h8 af[NKS];
#pragma unroll
    for (int ks = 0; ks < NKS; ++ks)
        af[ks] = *(const h8*)(x16 + (size_t)(node0 + ln) * DIN + ks * 32 + quad * 8);

    // ---- mm1 + BN + relu -> s_t (f16) ----
#pragma unroll
    for (int nt = 0; nt < 8; ++nt) {
        const int col = nt * 16 + ln;
        const float bv = b1[col];
        f4 acc = {bv, bv, bv, bv};
#pragma unroll
        for (int ks = 0; ks < NKS; ++ks) {
            const h8 bf = *(const h8*)(w1t + (size_t)col * DIN + ks * 32 + quad * 8);
            acc = __builtin_amdgcn_mfma_f32_16x16x32_f16(af[ks], bf, acc, 0, 0, 0);
        }
        const float gv = gm[col], btv = bt[col];
#pragma unroll
        for (int r = 0; r < 4; ++r) {
            const float t = fmaxf(fmaf(acc[r] * BN_SCALE_C, gv, btv), 0.f);
            s_t[w][quad * 4 + r][col] = (_Float16)t;
        }
    }
    __syncthreads();

    // preload A-fragments of T
    h8 af2[4];
#pragma unroll
    for (int ks = 0; ks < 4; ++ks)
        af2[ks] = *(const h8*)&s_t[w][ln][ks * 32 + quad * 8];

    // ---- mm2 + relu -> h16 (or f32 h on last layer) ----
#pragma unroll
    for (int nt = 0; nt < 8; ++nt) {
        const int col = nt * 16 + ln;
        const float bv = b2[col];
        f4 acc = {bv, bv, bv, bv};
#pragma unroll
        for (int ks = 0; ks < 4; ++ks) {
            const h8 bf = *(const h8*)(w2t + (size_t)col * HID_C + ks * 32 + quad * 8);
            acc = __builtin_amdgcn_mfma_f32_16x16x32_f16(af2[ks], bf, acc, 0, 0, 0);
        }
#pragma unroll
        for (int r = 0; r < 4; ++r) {
            const int node = node0 + quad * 4 + r;
            const float v = fmaxf(acc[r], 0.f);
            if (LASTL) {
                hout[(size_t)node * HID_C + col] = v;
            } else {
                h16out[(size_t)node * HID_C + col] = (_Float16)v;
            }
        }
    }
}

// ---------------------------------------------------------------------------
// Pool + output MLP (unchanged).
// ---------------------------------------------------------------------------
__global__ __launch_bounds__(256) void pool_kernel(
    const float* __restrict__ hfin, const int* __restrict__ batch,
    const float* __restrict__ w1, const float* __restrict__ b1,
    const float* __restrict__ w2, const float* __restrict__ b2,
    float* __restrict__ out, int n_nodes)
{
    const int gid = blockIdx.x;

    int lo = 0, hi = n_nodes;
    while (lo < hi) { int mid = (lo + hi) >> 1; if (batch[mid] < gid) lo = mid + 1; else hi = mid; }
    const int start = lo;
    hi = n_nodes;
    while (lo < hi) { int mid = (lo + hi) >> 1; if (batch[mid] < gid + 1) lo = mid + 1; else hi = mid; }
    const int end = lo;

    const int f = threadIdx.x & (HID_C - 1);
    const int half = threadIdx.x >> 7;

    float sum = 0.f;
    for (int n = start + half; n < end; n += 2)
        sum += hfin[(size_t)n * HID_C + f];

    __shared__ float s_sum[2][HID_C];
    __shared__ float s_p[HID_C];
    __shared__ float s_t[HID_C];
    s_sum[half][f] = sum;
    __syncthreads();

    if (threadIdx.x < HID_C) {
        const float cnt = (float)(end - start);
        s_p[f] = (s_sum[0][f] + s_sum[1][f]) / fmaxf(cnt, 1.f);
    }
    __syncthreads();

    if (threadIdx.x < HID_C) {
        float acc = b1[f];
        for (int k = 0; k < HID_C; ++k) acc = fmaf(s_p[k], w1[k * HID_C + f], acc);
        s_t[f] = fmaxf(acc, 0.f);
    }
    __syncthreads();

    if (threadIdx.x < HID_C) {
        float acc = b2[f];
        for (int k = 0; k < HID_C; ++k) acc = fmaf(s_t[k], w2[k * HID_C + f], acc);
        out[(size_t)gid * HID_C + f] = acc;
    }
}

// ---------------------------------------------------------------------------
extern "C" void kernel_launch(void* const* d_in, const int* in_sizes, int n_in,
                              void* d_out, int out_size, void* d_ws, size_t ws_size,
                              hipStream_t stream)
{
    const float* x         = (const float*)d_in[0];
    const float* edge_attr = (const float*)d_in[1];
    const int*   edge_index= (const int*)  d_in[2];
    const int*   batch     = (const int*)  d_in[3];
    const int*   src = edge_index;
    const int*   dst = edge_index + N_EDGES_C;

    const float* el_w[3] = {(const float*)d_in[4],  (const float*)d_in[12], (const float*)d_in[20]};
    const float* el_b[3] = {(const float*)d_in[5],  (const float*)d_in[13], (const float*)d_in[21]};
    const float* c_w1[3] = {(const float*)d_in[6],  (const float*)d_in[14], (const float*)d_in[22]};
    const float* c_b1[3] = {(const float*)d_in[7],  (const float*)d_in[15], (const float*)d_in[23]};
    const float* c_g [3] = {(const float*)d_in[8],  (const float*)d_in[16], (const float*)d_in[24]};
    const float* c_bt[3] = {(const float*)d_in[9],  (const float*)d_in[17], (const float*)d_in[25]};
    const float* c_w2[3] = {(const float*)d_in[10], (const float*)d_in[18], (const float*)d_in[26]};
    const float* c_b2[3] = {(const float*)d_in[11], (const float*)d_in[19], (const float*)d_in[27]};
    const float* o_w1 = (const float*)d_in[28];
    const float* o_b1 = (const float*)d_in[29];
    const float* o_w2 = (const float*)d_in[30];
    const float* o_b2 = (const float*)d_in[31];

    // ---- workspace layout (~200 MB) ----
    char* wsp = (char*)d_ws;
    size_t used = 0;
    auto alloc = [&](size_t bytes) { char* p = wsp + used; used += (bytes + 255) & ~(size_t)255; return p; };
    float* h        = (float*)alloc((size_t)N_NODES_C * HID_C * 4);   // final f32 (pool input)
    int*   counts   = (int*)alloc((size_t)N_NODES_C * 4);
    int*   incl     = (int*)alloc((size_t)N_NODES_C * 4);
    int*   rowstart = (int*)alloc((size_t)N_NODES_C * 4);
    int*   cursor   = (int*)alloc((size_t)N_NODES_C * 4);
    int*   blocksums= (int*)alloc(128 * 4);
    int*   blockoffs= (int*)alloc(128 * 4);
    int*   perm_src = (int*)alloc((size_t)N_EDGES_C * 4);
    int*   perm_eid = (int*)alloc((size_t)N_EDGES_C * 4);
    _Float16* ea_f16 = (_Float16*)alloc((size_t)N_EDGES_C * 16 * 2);
    _Float16* x16    = (_Float16*)alloc((size_t)N_NODES_C * HID_C * 2);
    _Float16* h16_a  = (_Float16*)alloc((size_t)N_NODES_C * HID_C * 2);
    _Float16* h16_b  = (_Float16*)alloc((size_t)N_NODES_C * HID_C * 2);
    _Float16* x_f16  = (_Float16*)alloc((size_t)N_NODES_C * 64 * 2);
    _Float16* w1t[3], *w2t[3];
    h2* ew16p[3];
    for (int l = 0; l < 3; ++l) {
        w1t[l] = (_Float16*)alloc((size_t)HID_C * HID_C * 2);
        w2t[l] = (_Float16*)alloc((size_t)HID_C * HID_C * 2);
        ew16p[l] = (h2*)alloc((size_t)HID_C * 8 * 4);   // DIN*8 h2, DIN<=128
    }
    (void)ws_size;

    // ---- CSR build (once; reused by all 3 layers) ----
    hipMemsetAsync(counts, 0, (size_t)N_NODES_C * 4, stream);
    hist_kernel<<<(N_EDGES_C + 255) / 256, 256, 0, stream>>>(dst, counts, N_EDGES_C);
    scan1_kernel<<<SCAN_NB, SCAN_B, 0, stream>>>(counts, incl, blocksums, N_NODES_C);
    scan2_kernel<<<1, 64, 0, stream>>>(blocksums, blockoffs, SCAN_NB);
    scan3_kernel<<<SCAN_NB, SCAN_B, 0, stream>>>(incl, blockoffs, N_NODES_C);
    initrows_kernel<<<(N_NODES_C + 255) / 256, 256, 0, stream>>>(incl, counts, rowstart,
                                                                 cursor, N_NODES_C);
    scatter_kernel<<<(N_EDGES_C + 255) / 256, 256, 0, stream>>>(src, dst, cursor,
                                                                perm_src, perm_eid, N_EDGES_C);
    permute_ea_f16_kernel<<<(N_EDGES_C + 255) / 256, 256, 0, stream>>>(
        edge_attr, perm_eid, (__half*)ea_f16, N_EDGES_C);
    cast_f16_kernel<<<(N_NODES_C * 64 / 4 + 255) / 256, 256, 0, stream>>>(
        x, x_f16, N_NODES_C * 64 / 4);
    for (int l = 0; l < 3; ++l) {
        const int K1 = (l == 0) ? 64 : HID_C;
        transpose_w_kernel<<<(K1 * HID_C + 255) / 256, 256, 0, stream>>>(
            c_w1[l], w1t[l], K1, HID_C);
        transpose_w_kernel<<<(HID_C * HID_C + 255) / 256, 256, 0, stream>>>(
            c_w2[l], w2t[l], HID_C, HID_C);
        const int din = (l == 0) ? 64 : HID_C;
        pack_ew_kernel<<<(din * 8 + 255) / 256, 256, 0, stream>>>(
            el_w[l], ew16p[l], din);
    }

    const int n_tiles = N_NODES_C / 16;            // 6250
    const int nb_node = (n_tiles + 3) / 4;         // 1563

    // ---- 3 GINE layers (split: high-TLP agg -> MFMA node MLP) ----
    // layer 0 (DIN=64)
    gine_agg_kernel<64><<<(N_NODES_C + 15) / 16, 256, 0, stream>>>(
        x_f16, ea_f16, perm_src, rowstart, incl, ew16p[0], el_b[0],
        x16, N_NODES_C);
    node_mfma_kernel<64, false><<<nb_node, 256, 0, stream>>>(
        x16, w1t[0], c_b1[0], c_g[0], c_bt[0], w2t[0], c_b2[0],
        h, h16_a, n_tiles);
    // layer 1
    gine_agg_kernel<128><<<(N_NODES_C + 7) / 8, 256, 0, stream>>>(
        h16_a, ea_f16, perm_src, rowstart, incl, ew16p[1], el_b[1],
        x16, N_NODES_C);
    node_mfma_kernel<128, false><<<nb_node, 256, 0, stream>>>(
        x16, w1t[1], c_b1[1], c_g[1], c_bt[1], w2t[1], c_b2[1],
        h, h16_b, n_tiles);
    // layer 2
    gine_agg_kernel<128><<<(N_NODES_C + 7) / 8, 256, 0, stream>>>(
        h16_b, ea_f16, perm_src, rowstart, incl, ew16p[2], el_b[2],
        x16, N_NODES_C);
    node_mfma_kernel<128, true><<<nb_node, 256, 0, stream>>>(
        x16, w1t[2], c_b1[2], c_g[2], c_bt[2], w2t[2], c_b2[2],
        h, h16_a, n_tiles);

    // ---- pool + output MLP ----
    pool_kernel<<<N_GRAPHS_C, 256, 0, stream>>>(h, batch, o_w1, o_b1, o_w2, o_b2,
                                                (float*)d_out, N_NODES_C);
}

// Round 8
// 1148.260 us; speedup vs baseline: 1.1090x; 1.0309x over previous
//
#include <hip/hip_runtime.h>
#include <hip/hip_fp16.h>
#include <cstdint>
#include <cstddef>

#define N_NODES_C  100000
#define N_EDGES_C  1600000
#define N_GRAPHS_C 256
#define HID_C      128
// 1/sqrt(1+1e-5)
#define BN_SCALE_C 0.9999950000374997f

#define SCAN_B 1024
#define SCAN_NB ((N_NODES_C + SCAN_B - 1) / SCAN_B)   // 98

typedef _Float16 h2 __attribute__((ext_vector_type(2)));
typedef _Float16 h4 __attribute__((ext_vector_type(4)));
typedef _Float16 h8 __attribute__((ext_vector_type(8)));
typedef float    f4 __attribute__((ext_vector_type(4)));

struct __align__(16) EA8 { h2 p[4]; };       // 8 fp16 = 16 B
struct __align__(8)  HQ  { h2 a, b; };       // 4 fp16 = 8 B
struct __align__(16) H8  { __half2 v[4]; };  // preamble convert

#if defined(__has_builtin)
#  if __has_builtin(__builtin_amdgcn_fdot2)
#    define HAVE_FDOT2 1
#  endif
#endif
#ifndef HAVE_FDOT2
#  define HAVE_FDOT2 0
#endif

__device__ __forceinline__ float fdot2_(h2 a, h2 b, float c)
{
#if HAVE_FDOT2
    return __builtin_amdgcn_fdot2(a, b, c, false);
#else
    return c + (float)a[0] * (float)b[0] + (float)a[1] * (float)b[1];
#endif
}

// ---------------------------------------------------------------------------
// CSR build: histogram of dst, inclusive scan, scatter edge ids.
// ---------------------------------------------------------------------------
__global__ __launch_bounds__(256) void hist_kernel(
    const int* __restrict__ dst, int* __restrict__ counts, int n_edges)
{
    int e = blockIdx.x * 256 + threadIdx.x;
    if (e < n_edges) atomicAdd(&counts[dst[e]], 1);
}

__global__ __launch_bounds__(SCAN_B) void scan1_kernel(
    const int* __restrict__ counts, int* __restrict__ incl,
    int* __restrict__ blocksums, int n)
{
    __shared__ int sdata[SCAN_B];
    const int lid = threadIdx.x;
    const int i = blockIdx.x * SCAN_B + lid;
    sdata[lid] = (i < n) ? counts[i] : 0;
    __syncthreads();
#pragma unroll
    for (int off = 1; off < SCAN_B; off <<= 1) {
        int t = (lid >= off) ? sdata[lid - off] : 0;
        __syncthreads();
        sdata[lid] += t;
        __syncthreads();
    }
    if (i < n) incl[i] = sdata[lid];
    if (lid == SCAN_B - 1) blocksums[blockIdx.x] = sdata[lid];
}

__global__ void scan2_kernel(const int* __restrict__ blocksums,
                             int* __restrict__ blockoffs, int nb)
{
    if (threadIdx.x == 0 && blockIdx.x == 0) {
        int off = 0;
        for (int b = 0; b < nb; ++b) { blockoffs[b] = off; off += blocksums[b]; }
    }
}

__global__ __launch_bounds__(SCAN_B) void scan3_kernel(
    int* __restrict__ incl, const int* __restrict__ blockoffs, int n)
{
    const int i = blockIdx.x * SCAN_B + threadIdx.x;
    if (i < n) incl[i] += blockoffs[blockIdx.x];
}

__global__ __launch_bounds__(256) void initrows_kernel(
    const int* __restrict__ incl, const int* __restrict__ counts,
    int* __restrict__ rowstart, int* __restrict__ cursor, int n)
{
    const int i = blockIdx.x * 256 + threadIdx.x;
    if (i < n) {
        const int rs = incl[i] - counts[i];
        rowstart[i] = rs;
        cursor[i]   = rs;
    }
}

// Two 4B random stores per edge; agg hot loop then reads only perm_src (4B).
__global__ __launch_bounds__(256) void scatter_kernel(
    const int* __restrict__ src, const int* __restrict__ dst,
    int* __restrict__ cursor, int* __restrict__ perm_src,
    int* __restrict__ perm_eid, int n_edges)
{
    const int e = blockIdx.x * 256 + threadIdx.x;
    if (e < n_edges) {
        const int pos = atomicAdd(&cursor[dst[e]], 1);
        perm_src[pos] = src[e];
        perm_eid[pos] = e;
    }
}

// Gather edge_attr rows into CSR order AND convert to fp16 pairs.
__global__ __launch_bounds__(256) void permute_ea_f16_kernel(
    const float* __restrict__ edge_attr, const int* __restrict__ perm_eid,
    __half* __restrict__ ea_f16, int n_edges)
{
    const int j = blockIdx.x * 256 + threadIdx.x;
    if (j >= n_edges) return;
    const int eid = perm_eid[j];
    const float4* p = (const float4*)(edge_attr + (size_t)eid * 16);
    const float4 q0 = p[0], q1 = p[1], q2 = p[2], q3 = p[3];
    H8 a, b;
    a.v[0] = __floats2half2_rn(q0.x, q0.y);
    a.v[1] = __floats2half2_rn(q0.z, q0.w);
    a.v[2] = __floats2half2_rn(q1.x, q1.y);
    a.v[3] = __floats2half2_rn(q1.z, q1.w);
    b.v[0] = __floats2half2_rn(q2.x, q2.y);
    b.v[1] = __floats2half2_rn(q2.z, q2.w);
    b.v[2] = __floats2half2_rn(q3.x, q3.y);
    b.v[3] = __floats2half2_rn(q3.z, q3.w);
    H8* o = (H8*)(ea_f16 + (size_t)j * 16);
    o[0] = a;
    o[1] = b;
}

// Cast fp32 array -> f16 (vectorized by 4).
__global__ __launch_bounds__(256) void cast_f16_kernel(
    const float* __restrict__ in, _Float16* __restrict__ out, int n4)
{
    const int i = blockIdx.x * 256 + threadIdx.x;
    if (i >= n4) return;
    const float4 v = ((const float4*)in)[i];
    h4 o; o[0] = (_Float16)v.x; o[1] = (_Float16)v.y;
    o[2] = (_Float16)v.z; o[3] = (_Float16)v.w;
    *(h4*)(out + (size_t)i * 4) = o;
}

// Transpose + cast weights: wt[n][k] = (f16) w[k][n].  (tiny, one-time)
__global__ __launch_bounds__(256) void transpose_w_kernel(
    const float* __restrict__ w, _Float16* __restrict__ wt, int K, int N)
{
    const int i = blockIdx.x * 256 + threadIdx.x;
    if (i >= K * N) return;
    const int n = i / K;
    const int k = i - n * K;
    wt[(size_t)n * K + k] = (_Float16)w[(size_t)k * N + n];
}

// Pack edge-MLP weights for the agg kernel: per output-quad fq, 32 h2
// values laid out contiguously (128 B, vector-loadable in the prologue).
// out[fq*32 + k2*4 + fi] = ( ew[2k2][fq*4+fi], ew[2k2+1][fq*4+fi] )
__global__ __launch_bounds__(256) void pack_ew_kernel(
    const float* __restrict__ ew, h2* __restrict__ out, int din)
{
    const int i = blockIdx.x * 256 + threadIdx.x;
    const int total = din * 8;             // (din/4) * 32
    if (i >= total) return;
    const int fq = i >> 5, r = i & 31, k2 = r >> 2, fi = r & 3;
    const int f = fq * 4 + fi;
    h2 t;
    t[0] = (_Float16)ew[(size_t)(2 * k2)     * din + f];
    t[1] = (_Float16)ew[(size_t)(2 * k2 + 1) * din + f];
    out[i] = t;
}

// ---------------------------------------------------------------------------
// Edge MLP for one edge (lane's 4 output features) via fdot2.
// ---------------------------------------------------------------------------
__device__ __forceinline__ float4 eamlp2(const EA8 a0, const EA8 c0,
                                         const h2 (&ew2h)[8][4], const float4 ebv)
{
    float4 m = {ebv.x, ebv.y, ebv.z, ebv.w};
#pragma unroll
    for (int k = 0; k < 4; ++k) {
        m.x = fdot2_(a0.p[k], ew2h[k][0], m.x);
        m.y = fdot2_(a0.p[k], ew2h[k][1], m.y);
        m.z = fdot2_(a0.p[k], ew2h[k][2], m.z);
        m.w = fdot2_(a0.p[k], ew2h[k][3], m.w);
    }
#pragma unroll
    for (int k = 0; k < 4; ++k) {
        m.x = fdot2_(c0.p[k], ew2h[4 + k][0], m.x);
        m.y = fdot2_(c0.p[k], ew2h[4 + k][1], m.y);
        m.z = fdot2_(c0.p[k], ew2h[4 + k][2], m.z);
        m.w = fdot2_(c0.p[k], ew2h[4 + k][3], m.w);
    }
    return m;
}

// One batch = 4 edges. Loads issued in consumption order (perm -> ea -> hq)
// so in-order vmcnt retirement lets compute of edge u overlap later gathers.
struct EBatch {
    int sn[4];
    EA8 a[4], c[4];
    HQ  hq[4];
};

template<int DIN>
__device__ __forceinline__ void load_batch(
    const _Float16* __restrict__ hin, const _Float16* __restrict__ ea16,
    const int* __restrict__ perm_src, int j, int fq, EBatch& b)
{
#pragma unroll
    for (int u = 0; u < 4; ++u) b.sn[u] = perm_src[j + u];
#pragma unroll
    for (int u = 0; u < 4; ++u) {
        const EA8* pe = (const EA8*)(ea16 + (size_t)(j + u) * 16);
        b.a[u] = pe[0];
        b.c[u] = pe[1];
    }
#pragma unroll
    for (int u = 0; u < 4; ++u)
        b.hq[u] = *(const HQ*)(hin + (size_t)b.sn[u] * DIN + fq * 4);
}

__device__ __forceinline__ void compute_batch(
    const EBatch& b, const h2 (&ew2h)[8][4], const float4 ebv, float4& acc)
{
#pragma unroll
    for (int u = 0; u < 4; ++u) {
        const float4 m = eamlp2(b.a[u], b.c[u], ew2h, ebv);
        acc.x += fmaxf(m.x + (float)b.hq[u].a[0], 0.f);
        acc.y += fmaxf(m.y + (float)b.hq[u].a[1], 0.f);
        acc.z += fmaxf(m.z + (float)b.hq[u].b[0], 0.f);
        acc.w += fmaxf(m.w + (float)b.hq[u].b[1], 0.f);
    }
}

// ---------------------------------------------------------------------------
// CSR aggregate (high-TLP: one node per 32/16-lane slot, no barriers).
// 2-deep software pipeline of 4-edge batches (8 gathers in flight):
// load batch k+1, then compute batch k -- HBM/L3 gather latency hides
// under the ~300cy of edge-MLP compute. Ping-pong named batches (no
// runtime indexing -> stays in registers).
// ---------------------------------------------------------------------------
template<int DIN>
__global__ __launch_bounds__(256) void gine_agg_kernel(
    const _Float16* __restrict__ hin, const _Float16* __restrict__ ea16,
    const int* __restrict__ perm_src,
    const int* __restrict__ rowstart, const int* __restrict__ rowend,
    const h2* __restrict__ ew16, const float* __restrict__ eb,
    _Float16* __restrict__ x16, int n_nodes)
{
    constexpr int NQ    = DIN / 4;
    constexpr int SLOTS = 256 / NQ;
    const int fq   = threadIdx.x & (NQ - 1);
    const int slot = threadIdx.x / NQ;
    const int v = blockIdx.x * SLOTS + slot;
    if (v >= n_nodes) return;

    // packed f16 edge weights: contiguous 128 B -> compiler merges loads.
    h2 ew2h[8][4];
    {
        const h2* wl = ew16 + (size_t)fq * 32;
#pragma unroll
        for (int k2 = 0; k2 < 8; ++k2)
#pragma unroll
            for (int fi = 0; fi < 4; ++fi)
                ew2h[k2][fi] = wl[k2 * 4 + fi];
    }
    const float4 ebv = *(const float4*)(eb + fq * 4);

    const int s0 = rowstart[v];
    const int s1 = rowend[v];

    // residual row (own node): issue early, independent of the loop
    const HQ hv = *(const HQ*)(hin + (size_t)v * DIN + fq * 4);

    float4 acc = {0.f, 0.f, 0.f, 0.f};
    int j = s0;
    const int nfull = (s1 - s0) >> 2;

    if (nfull > 0) {
        EBatch b0, b1;
        load_batch<DIN>(hin, ea16, perm_src, j, fq, b0);
        int it = 1;
        for (; it + 1 < nfull; it += 2) {
            load_batch<DIN>(hin, ea16, perm_src, j + 4, fq, b1);
            compute_batch(b0, ew2h, ebv, acc);
            load_batch<DIN>(hin, ea16, perm_src, j + 8, fq, b0);
            compute_batch(b1, ew2h, ebv, acc);
            j += 8;
        }
        if (it < nfull) {
            load_batch<DIN>(hin, ea16, perm_src, j + 4, fq, b1);
            compute_batch(b0, ew2h, ebv, acc);
            compute_batch(b1, ew2h, ebv, acc);
            j += 8;
        } else {
            compute_batch(b0, ew2h, ebv, acc);
            j += 4;
        }
    }
    // tail: 0-3 edges
    for (; j < s1; ++j) {
        const int sn = perm_src[j];
        const EA8* pe = (const EA8*)(ea16 + (size_t)j * 16);
        const EA8 a = pe[0], c = pe[1];
        const HQ hq = *(const HQ*)(hin + (size_t)sn * DIN + fq * 4);
        const float4 m = eamlp2(a, c, ew2h, ebv);
        acc.x += fmaxf(m.x + (float)hq.a[0], 0.f);
        acc.y += fmaxf(m.y + (float)hq.a[1], 0.f);
        acc.z += fmaxf(m.z + (float)hq.b[0], 0.f);
        acc.w += fmaxf(m.w + (float)hq.b[1], 0.f);
    }

    // residual + f16 store: x = h_v + agg
    h4 o;
    o[0] = (_Float16)(acc.x + (float)hv.a[0]);
    o[1] = (_Float16)(acc.y + (float)hv.a[1]);
    o[2] = (_Float16)(acc.z + (float)hv.b[0]);
    o[3] = (_Float16)(acc.w + (float)hv.b[1]);
    *(h4*)(x16 + (size_t)v * DIN + fq * 4) = o;
}

// ---------------------------------------------------------------------------
// Node MLP: 4 waves per block, 1 tile (16 nodes) per wave. A-fragments for
// mm1 read DIRECTLY from global x16 (f16) -- no s_x staging. s_t LDS only
// for the mm1->mm2 transpose. Writes f16 h (next layer) or f32 h (pool).
// ---------------------------------------------------------------------------
template<int DIN, bool LASTL>
__global__ __launch_bounds__(256) void node_mfma_kernel(
    const _Float16* __restrict__ x16,
    const _Float16* __restrict__ w1t, const float* __restrict__ b1,
    const float* __restrict__ gm, const float* __restrict__ bt,
    const _Float16* __restrict__ w2t, const float* __restrict__ b2,
    float* __restrict__ hout, _Float16* __restrict__ h16out, int n_tiles)
{
    constexpr int STP = HID_C + 8;
    __shared__ _Float16 s_t[4][16][STP];

    const int w    = threadIdx.x >> 6;
    const int lane = threadIdx.x & 63;
    int tile = blockIdx.x * 4 + w;
    if (tile >= n_tiles) tile = n_tiles - 1;   // clamp: keep barriers uniform
    const int node0 = tile * 16;
    const int ln   = lane & 15;
    const int quad = lane >> 4;

    // preload A-fragments of X (row ln, cols quad*8 + ks*32) from global
    constexpr int NKS = DIN / 32;
    h8 af[NKS];
#pragma unroll
    for (int ks = 0; ks < NKS; ++ks)
        af[ks] = *(const h8*)(x16 + (size_t)(node0 + ln) * DIN + ks * 32 + quad * 8);

    // ---- mm1 + BN + relu -> s_t (f16) ----
#pragma unroll
    for (int nt = 0; nt < 8; ++nt) {
        const int col = nt * 16 + ln;
        const float bv = b1[col];
        f4 acc = {bv, bv, bv, bv};
#pragma unroll
        for (int ks = 0; ks < NKS; ++ks) {
            const h8 bf = *(const h8*)(w1t + (size_t)col * DIN + ks * 32 + quad * 8);
            acc = __builtin_amdgcn_mfma_f32_16x16x32_f16(af[ks], bf, acc, 0, 0, 0);
        }
        const float gv = gm[col], btv = bt[col];
#pragma unroll
        for (int r = 0; r < 4; ++r) {
            const float t = fmaxf(fmaf(acc[r] * BN_SCALE_C, gv, btv), 0.f);
            s_t[w][quad * 4 + r][col] = (_Float16)t;
        }
    }
    __syncthreads();

    // preload A-fragments of T
    h8 af2[4];
#pragma unroll
    for (int ks = 0; ks < 4; ++ks)
        af2[ks] = *(const h8*)&s_t[w][ln][ks * 32 + quad * 8];

    // ---- mm2 + relu -> h16 (or f32 h on last layer) ----
#pragma unroll
    for (int nt = 0; nt < 8; ++nt) {
        const int col = nt * 16 + ln;
        const float bv = b2[col];
        f4 acc = {bv, bv, bv, bv};
#pragma unroll
        for (int ks = 0; ks < 4; ++ks) {
            const h8 bf = *(const h8*)(w2t + (size_t)col * HID_C + ks * 32 + quad * 8);
            acc = __builtin_amdgcn_mfma_f32_16x16x32_f16(af2[ks], bf, acc, 0, 0, 0);
        }
#pragma unroll
        for (int r = 0; r < 4; ++r) {
            const int node = node0 + quad * 4 + r;
            const float v = fmaxf(acc[r], 0.f);
            if (LASTL) {
                hout[(size_t)node * HID_C + col] = v;
            } else {
                h16out[(size_t)node * HID_C + col] = (_Float16)v;
            }
        }
    }
}

// ---------------------------------------------------------------------------
// Pool + output MLP (unchanged).
// ---------------------------------------------------------------------------
__global__ __launch_bounds__(256) void pool_kernel(
    const float* __restrict__ hfin, const int* __restrict__ batch,
    const float* __restrict__ w1, const float* __restrict__ b1,
    const float* __restrict__ w2, const float* __restrict__ b2,
    float* __restrict__ out, int n_nodes)
{
    const int gid = blockIdx.x;

    int lo = 0, hi = n_nodes;
    while (lo < hi) { int mid = (lo + hi) >> 1; if (batch[mid] < gid) lo = mid + 1; else hi = mid; }
    const int start = lo;
    hi = n_nodes;
    while (lo < hi) { int mid = (lo + hi) >> 1; if (batch[mid] < gid + 1) lo = mid + 1; else hi = mid; }
    const int end = lo;

    const int f = threadIdx.x & (HID_C - 1);
    const int half = threadIdx.x >> 7;

    float sum = 0.f;
    for (int n = start + half; n < end; n += 2)
        sum += hfin[(size_t)n * HID_C + f];

    __shared__ float s_sum[2][HID_C];
    __shared__ float s_p[HID_C];
    __shared__ float s_t[HID_C];
    s_sum[half][f] = sum;
    __syncthreads();

    if (threadIdx.x < HID_C) {
        const float cnt = (float)(end - start);
        s_p[f] = (s_sum[0][f] + s_sum[1][f]) / fmaxf(cnt, 1.f);
    }
    __syncthreads();

    if (threadIdx.x < HID_C) {
        float acc = b1[f];
        for (int k = 0; k < HID_C; ++k) acc = fmaf(s_p[k], w1[k * HID_C + f], acc);
        s_t[f] = fmaxf(acc, 0.f);
    }
    __syncthreads();

    if (threadIdx.x < HID_C) {
        float acc = b2[f];
        for (int k = 0; k < HID_C; ++k) acc = fmaf(s_t[k], w2[k * HID_C + f], acc);
        out[(size_t)gid * HID_C + f] = acc;
    }
}

// ---------------------------------------------------------------------------
extern "C" void kernel_launch(void* const* d_in, const int* in_sizes, int n_in,
                              void* d_out, int out_size, void* d_ws, size_t ws_size,
                              hipStream_t stream)
{
    const float* x         = (const float*)d_in[0];
    const float* edge_attr = (const float*)d_in[1];
    const int*   edge_index= (const int*)  d_in[2];
    const int*   batch     = (const int*)  d_in[3];
    const int*   src = edge_index;
    const int*   dst = edge_index + N_EDGES_C;

    const float* el_w[3] = {(const float*)d_in[4],  (const float*)d_in[12], (const float*)d_in[20]};
    const float* el_b[3] = {(const float*)d_in[5],  (const float*)d_in[13], (const float*)d_in[21]};
    const float* c_w1[3] = {(const float*)d_in[6],  (const float*)d_in[14], (const float*)d_in[22]};
    const float* c_b1[3] = {(const float*)d_in[7],  (const float*)d_in[15], (const float*)d_in[23]};
    const float* c_g [3] = {(const float*)d_in[8],  (const float*)d_in[16], (const float*)d_in[24]};
    const float* c_bt[3] = {(const float*)d_in[9],  (const float*)d_in[17], (const float*)d_in[25]};
    const float* c_w2[3] = {(const float*)d_in[10], (const float*)d_in[18], (const float*)d_in[26]};
    const float* c_b2[3] = {(const float*)d_in[11], (const float*)d_in[19], (const float*)d_in[27]};
    const float* o_w1 = (const float*)d_in[28];
    const float* o_b1 = (const float*)d_in[29];
    const float* o_w2 = (const float*)d_in[30];
    const float* o_b2 = (const float*)d_in[31];

    // ---- workspace layout (~200 MB) ----
    char* wsp = (char*)d_ws;
    size_t used = 0;
    auto alloc = [&](size_t bytes) { char* p = wsp + used; used += (bytes + 255) & ~(size_t)255; return p; };
    float* h        = (float*)alloc((size_t)N_NODES_C * HID_C * 4);   // final f32 (pool input)
    int*   counts   = (int*)alloc((size_t)N_NODES_C * 4);
    int*   incl     = (int*)alloc((size_t)N_NODES_C * 4);
    int*   rowstart = (int*)alloc((size_t)N_NODES_C * 4);
    int*   cursor   = (int*)alloc((size_t)N_NODES_C * 4);
    int*   blocksums= (int*)alloc(128 * 4);
    int*   blockoffs= (int*)alloc(128 * 4);
    int*   perm_src = (int*)alloc((size_t)N_EDGES_C * 4);
    int*   perm_eid = (int*)alloc((size_t)N_EDGES_C * 4);
    _Float16* ea_f16 = (_Float16*)alloc((size_t)N_EDGES_C * 16 * 2);
    _Float16* x16    = (_Float16*)alloc((size_t)N_NODES_C * HID_C * 2);
    _Float16* h16_a  = (_Float16*)alloc((size_t)N_NODES_C * HID_C * 2);
    _Float16* h16_b  = (_Float16*)alloc((size_t)N_NODES_C * HID_C * 2);
    _Float16* x_f16  = (_Float16*)alloc((size_t)N_NODES_C * 64 * 2);
    _Float16* w1t[3], *w2t[3];
    h2* ew16p[3];
    for (int l = 0; l < 3; ++l) {
        w1t[l] = (_Float16*)alloc((size_t)HID_C * HID_C * 2);
        w2t[l] = (_Float16*)alloc((size_t)HID_C * HID_C * 2);
        ew16p[l] = (h2*)alloc((size_t)HID_C * 8 * 4);   // DIN*8 h2, DIN<=128
    }
    (void)ws_size;

    // ---- CSR build (once; reused by all 3 layers) ----
    hipMemsetAsync(counts, 0, (size_t)N_NODES_C * 4, stream);
    hist_kernel<<<(N_EDGES_C + 255) / 256, 256, 0, stream>>>(dst, counts, N_EDGES_C);
    scan1_kernel<<<SCAN_NB, SCAN_B, 0, stream>>>(counts, incl, blocksums, N_NODES_C);
    scan2_kernel<<<1, 64, 0, stream>>>(blocksums, blockoffs, SCAN_NB);
    scan3_kernel<<<SCAN_NB, SCAN_B, 0, stream>>>(incl, blockoffs, N_NODES_C);
    initrows_kernel<<<(N_NODES_C + 255) / 256, 256, 0, stream>>>(incl, counts, rowstart,
                                                                 cursor, N_NODES_C);
    scatter_kernel<<<(N_EDGES_C + 255) / 256, 256, 0, stream>>>(src, dst, cursor,
                                                                perm_src, perm_eid, N_EDGES_C);
    permute_ea_f16_kernel<<<(N_EDGES_C + 255) / 256, 256, 0, stream>>>(
        edge_attr, perm_eid, (__half*)ea_f16, N_EDGES_C);
    cast_f16_kernel<<<(N_NODES_C * 64 / 4 + 255) / 256, 256, 0, stream>>>(
        x, x_f16, N_NODES_C * 64 / 4);
    for (int l = 0; l < 3; ++l) {
        const int K1 = (l == 0) ? 64 : HID_C;
        transpose_w_kernel<<<(K1 * HID_C + 255) / 256, 256, 0, stream>>>(
            c_w1[l], w1t[l], K1, HID_C);
        transpose_w_kernel<<<(HID_C * HID_C + 255) / 256, 256, 0, stream>>>(
            c_w2[l], w2t[l], HID_C, HID_C);
        const int din = (l == 0) ? 64 : HID_C;
        pack_ew_kernel<<<(din * 8 + 255) / 256, 256, 0, stream>>>(
            el_w[l], ew16p[l], din);
    }

    const int n_tiles = N_NODES_C / 16;            // 6250
    const int nb_node = (n_tiles + 3) / 4;         // 1563

    // ---- 3 GINE layers (split: high-TLP agg -> MFMA node MLP) ----
    // layer 0 (DIN=64)
    gine_agg_kernel<64><<<(N_NODES_C + 15) / 16, 256, 0, stream>>>(
        x_f16, ea_f16, perm_src, rowstart, incl, ew16p[0], el_b[0],
        x16, N_NODES_C);
    node_mfma_kernel<64, false><<<nb_node, 256, 0, stream>>>(
        x16, w1t[0], c_b1[0], c_g[0], c_bt[0], w2t[0], c_b2[0],
        h, h16_a, n_tiles);
    // layer 1
    gine_agg_kernel<128><<<(N_NODES_C + 7) / 8, 256, 0, stream>>>(
        h16_a, ea_f16, perm_src, rowstart, incl, ew16p[1], el_b[1],
        x16, N_NODES_C);
    node_mfma_kernel<128, false><<<nb_node, 256, 0, stream>>>(
        x16, w1t[1], c_b1[1], c_g[1], c_bt[1], w2t[1], c_b2[1],
        h, h16_b, n_tiles);
    // layer 2
    gine_agg_kernel<128><<<(N_NODES_C + 7) / 8, 256, 0, stream>>>(
        h16_b, ea_f16, perm_src, rowstart, incl, ew16p[2], el_b[2],
        x16, N_NODES_C);
    node_mfma_kernel<128, true><<<nb_node, 256, 0, stream>>>(
        x16, w1t[2], c_b1[2], c_g[2], c_bt[2], w2t[2], c_b2[2],
        h, h16_a, n_tiles);

    // ---- pool + output MLP ----
    pool_kernel<<<N_GRAPHS_C, 256, 0, stream>>>(h, batch, o_w1, o_b1, o_w2, o_b2,
                                                (float*)d_out, N_NODES_C);
}

// Round 9
// 936.432 us; speedup vs baseline: 1.3599x; 1.2262x over previous
//
#include <hip/hip_runtime.h>
#include <hip/hip_fp16.h>
#include <cstdint>
#include <cstddef>

#define N_NODES_C  100000
#define N_EDGES_C  1600000
#define N_GRAPHS_C 256
#define HID_C      128
// 1/sqrt(1+1e-5)
#define BN_SCALE_C 0.9999950000374997f

#define SCAN_B 1024
#define SCAN_NB ((N_NODES_C + SCAN_B - 1) / SCAN_B)   // 98

typedef _Float16 h2 __attribute__((ext_vector_type(2)));
typedef _Float16 h4 __attribute__((ext_vector_type(4)));
typedef _Float16 h8 __attribute__((ext_vector_type(8)));
typedef float    f4 __attribute__((ext_vector_type(4)));

struct __align__(16) EA8 { h2 p[4]; };       // 8 fp16 = 16 B
struct __align__(8)  HQ  { h2 a, b; };       // 4 fp16 = 8 B
struct __align__(16) H8  { __half2 v[4]; };  // preamble convert

#if defined(__has_builtin)
#  if __has_builtin(__builtin_amdgcn_fdot2)
#    define HAVE_FDOT2 1
#  endif
#endif
#ifndef HAVE_FDOT2
#  define HAVE_FDOT2 0
#endif

__device__ __forceinline__ float fdot2_(h2 a, h2 b, float c)
{
#if HAVE_FDOT2
    return __builtin_amdgcn_fdot2(a, b, c, false);
#else
    return c + (float)a[0] * (float)b[0] + (float)a[1] * (float)b[1];
#endif
}

// ---------------------------------------------------------------------------
// CSR build: histogram of dst, inclusive scan, scatter edge ids.
// ---------------------------------------------------------------------------
__global__ __launch_bounds__(256) void hist_kernel(
    const int* __restrict__ dst, int* __restrict__ counts, int n_edges)
{
    int e = blockIdx.x * 256 + threadIdx.x;
    if (e < n_edges) atomicAdd(&counts[dst[e]], 1);
}

__global__ __launch_bounds__(SCAN_B) void scan1_kernel(
    const int* __restrict__ counts, int* __restrict__ incl,
    int* __restrict__ blocksums, int n)
{
    __shared__ int sdata[SCAN_B];
    const int lid = threadIdx.x;
    const int i = blockIdx.x * SCAN_B + lid;
    sdata[lid] = (i < n) ? counts[i] : 0;
    __syncthreads();
#pragma unroll
    for (int off = 1; off < SCAN_B; off <<= 1) {
        int t = (lid >= off) ? sdata[lid - off] : 0;
        __syncthreads();
        sdata[lid] += t;
        __syncthreads();
    }
    if (i < n) incl[i] = sdata[lid];
    if (lid == SCAN_B - 1) blocksums[blockIdx.x] = sdata[lid];
}

__global__ void scan2_kernel(const int* __restrict__ blocksums,
                             int* __restrict__ blockoffs, int nb)
{
    if (threadIdx.x == 0 && blockIdx.x == 0) {
        int off = 0;
        for (int b = 0; b < nb; ++b) { blockoffs[b] = off; off += blocksums[b]; }
    }
}

__global__ __launch_bounds__(SCAN_B) void scan3_kernel(
    int* __restrict__ incl, const int* __restrict__ blockoffs, int n)
{
    const int i = blockIdx.x * SCAN_B + threadIdx.x;
    if (i < n) incl[i] += blockoffs[blockIdx.x];
}

__global__ __launch_bounds__(256) void initrows_kernel(
    const int* __restrict__ incl, const int* __restrict__ counts,
    int* __restrict__ rowstart, int* __restrict__ cursor, int n)
{
    const int i = blockIdx.x * 256 + threadIdx.x;
    if (i < n) {
        const int rs = incl[i] - counts[i];
        rowstart[i] = rs;
        cursor[i]   = rs;
    }
}

// Fused scatter + edge_attr permute/convert: thread e reads its OWN
// edge_attr row (fully coalesced across threads -- rows are sequential),
// converts to f16, and writes the 32B row to the CSR slot pos.
// Deletes the old permute kernel's 102 MB random read and perm_eid.
__global__ __launch_bounds__(256) void scatter_ea_kernel(
    const int* __restrict__ src, const int* __restrict__ dst,
    int* __restrict__ cursor, int* __restrict__ perm_src,
    const float* __restrict__ edge_attr, __half* __restrict__ ea_f16,
    int n_edges)
{
    const int e = blockIdx.x * 256 + threadIdx.x;
    if (e >= n_edges) return;

    // coalesced read of this edge's 16 fp32 attrs (sequential rows)
    const float4* p = (const float4*)(edge_attr + (size_t)e * 16);
    const float4 q0 = p[0], q1 = p[1], q2 = p[2], q3 = p[3];

    const int pos = atomicAdd(&cursor[dst[e]], 1);
    perm_src[pos] = src[e];

    H8 a, b;
    a.v[0] = __floats2half2_rn(q0.x, q0.y);
    a.v[1] = __floats2half2_rn(q0.z, q0.w);
    a.v[2] = __floats2half2_rn(q1.x, q1.y);
    a.v[3] = __floats2half2_rn(q1.z, q1.w);
    b.v[0] = __floats2half2_rn(q2.x, q2.y);
    b.v[1] = __floats2half2_rn(q2.z, q2.w);
    b.v[2] = __floats2half2_rn(q3.x, q3.y);
    b.v[3] = __floats2half2_rn(q3.z, q3.w);
    H8* o = (H8*)(ea_f16 + (size_t)pos * 16);
    o[0] = a;
    o[1] = b;
}

// Cast fp32 array -> f16 (vectorized by 4).
__global__ __launch_bounds__(256) void cast_f16_kernel(
    const float* __restrict__ in, _Float16* __restrict__ out, int n4)
{
    const int i = blockIdx.x * 256 + threadIdx.x;
    if (i >= n4) return;
    const float4 v = ((const float4*)in)[i];
    h4 o; o[0] = (_Float16)v.x; o[1] = (_Float16)v.y;
    o[2] = (_Float16)v.z; o[3] = (_Float16)v.w;
    *(h4*)(out + (size_t)i * 4) = o;
}

// Transpose + cast weights: wt[n][k] = (f16) w[k][n].  (tiny, one-time)
__global__ __launch_bounds__(256) void transpose_w_kernel(
    const float* __restrict__ w, _Float16* __restrict__ wt, int K, int N)
{
    const int i = blockIdx.x * 256 + threadIdx.x;
    if (i >= K * N) return;
    const int n = i / K;
    const int k = i - n * K;
    wt[(size_t)n * K + k] = (_Float16)w[(size_t)k * N + n];
}

// ---------------------------------------------------------------------------
// Edge MLP for one edge (lane's 4 output features) via fdot2.
// ---------------------------------------------------------------------------
__device__ __forceinline__ float4 eamlp2(const EA8 a0, const EA8 c0,
                                         const h2 (*ew2h)[4], const float4 ebv)
{
    float4 m = {ebv.x, ebv.y, ebv.z, ebv.w};
#pragma unroll
    for (int k = 0; k < 4; ++k) {
        m.x = fdot2_(a0.p[k], ew2h[k][0], m.x);
        m.y = fdot2_(a0.p[k], ew2h[k][1], m.y);
        m.z = fdot2_(a0.p[k], ew2h[k][2], m.z);
        m.w = fdot2_(a0.p[k], ew2h[k][3], m.w);
    }
#pragma unroll
    for (int k = 0; k < 4; ++k) {
        m.x = fdot2_(c0.p[k], ew2h[4 + k][0], m.x);
        m.y = fdot2_(c0.p[k], ew2h[4 + k][1], m.y);
        m.z = fdot2_(c0.p[k], ew2h[4 + k][2], m.z);
        m.w = fdot2_(c0.p[k], ew2h[4 + k][3], m.w);
    }
    return m;
}

// ---------------------------------------------------------------------------
// CSR aggregate -- round-4 verified structure (145 us @ DIN=128):
// one node per 32/16-lane slot, no barriers; flat ILP-4 main loop with
// loads in consumption order (perm4 -> ea8 -> hq4) so edge-MLP compute
// overlaps the in-flight h-gathers; 2/1-wide tails.
// Adds residual h_v and writes x16 = h+agg as f16.
// ---------------------------------------------------------------------------
template<int DIN>
__global__ __launch_bounds__(256) void gine_agg_kernel(
    const _Float16* __restrict__ hin, const _Float16* __restrict__ ea16,
    const int* __restrict__ perm_src,
    const int* __restrict__ rowstart, const int* __restrict__ rowend,
    const float* __restrict__ ew, const float* __restrict__ eb,
    _Float16* __restrict__ x16, int n_nodes)
{
    constexpr int NQ    = DIN / 4;
    constexpr int SLOTS = 256 / NQ;
    const int fq   = threadIdx.x & (NQ - 1);
    const int slot = threadIdx.x / NQ;
    const int v = blockIdx.x * SLOTS + slot;
    if (v >= n_nodes) return;

    h2 ew2h[8][4];
#pragma unroll
    for (int k2 = 0; k2 < 8; ++k2)
#pragma unroll
        for (int fi = 0; fi < 4; ++fi) {
            h2 t;
            t[0] = (_Float16)ew[(size_t)(2 * k2)     * DIN + fq * 4 + fi];
            t[1] = (_Float16)ew[(size_t)(2 * k2 + 1) * DIN + fq * 4 + fi];
            ew2h[k2][fi] = t;
        }
    const float4 ebv = *(const float4*)(eb + fq * 4);

    const int s0 = rowstart[v];
    const int s1 = rowend[v];

    float4 acc = {0.f, 0.f, 0.f, 0.f};
    int j = s0;

    // ---- 4-wide: loads issued up front, in consumption order ----
    for (; j + 4 <= s1; j += 4) {
        const int sn0 = perm_src[j + 0];
        const int sn1 = perm_src[j + 1];
        const int sn2 = perm_src[j + 2];
        const int sn3 = perm_src[j + 3];
        const EA8* pe = (const EA8*)(ea16 + (size_t)j * 16);
        const EA8 a0 = pe[0], c0 = pe[1], a1 = pe[2], c1 = pe[3];
        const EA8 a2 = pe[4], c2 = pe[5], a3 = pe[6], c3 = pe[7];
        const HQ hq0 = *(const HQ*)(hin + (size_t)sn0 * DIN + fq * 4);
        const HQ hq1 = *(const HQ*)(hin + (size_t)sn1 * DIN + fq * 4);
        const HQ hq2 = *(const HQ*)(hin + (size_t)sn2 * DIN + fq * 4);
        const HQ hq3 = *(const HQ*)(hin + (size_t)sn3 * DIN + fq * 4);

        const float4 m0 = eamlp2(a0, c0, ew2h, ebv);
        const float4 m1 = eamlp2(a1, c1, ew2h, ebv);
        const float4 m2 = eamlp2(a2, c2, ew2h, ebv);
        const float4 m3 = eamlp2(a3, c3, ew2h, ebv);

        acc.x += fmaxf(m0.x + (float)hq0.a[0], 0.f) + fmaxf(m1.x + (float)hq1.a[0], 0.f)
               + fmaxf(m2.x + (float)hq2.a[0], 0.f) + fmaxf(m3.x + (float)hq3.a[0], 0.f);
        acc.y += fmaxf(m0.y + (float)hq0.a[1], 0.f) + fmaxf(m1.y + (float)hq1.a[1], 0.f)
               + fmaxf(m2.y + (float)hq2.a[1], 0.f) + fmaxf(m3.y + (float)hq3.a[1], 0.f);
        acc.z += fmaxf(m0.z + (float)hq0.b[0], 0.f) + fmaxf(m1.z + (float)hq1.b[0], 0.f)
               + fmaxf(m2.z + (float)hq2.b[0], 0.f) + fmaxf(m3.z + (float)hq3.b[0], 0.f);
        acc.w += fmaxf(m0.w + (float)hq0.b[1], 0.f) + fmaxf(m1.w + (float)hq1.b[1], 0.f)
               + fmaxf(m2.w + (float)hq2.b[1], 0.f) + fmaxf(m3.w + (float)hq3.b[1], 0.f);
    }
    // ---- 2-wide remainder ----
    if (j + 2 <= s1) {
        const int sn0 = perm_src[j + 0];
        const int sn1 = perm_src[j + 1];
        const EA8* pe = (const EA8*)(ea16 + (size_t)j * 16);
        const EA8 a0 = pe[0], c0 = pe[1], a1 = pe[2], c1 = pe[3];
        const HQ hq0 = *(const HQ*)(hin + (size_t)sn0 * DIN + fq * 4);
        const HQ hq1 = *(const HQ*)(hin + (size_t)sn1 * DIN + fq * 4);
        const float4 m0 = eamlp2(a0, c0, ew2h, ebv);
        const float4 m1 = eamlp2(a1, c1, ew2h, ebv);
        acc.x += fmaxf(m0.x + (float)hq0.a[0], 0.f) + fmaxf(m1.x + (float)hq1.a[0], 0.f);
        acc.y += fmaxf(m0.y + (float)hq0.a[1], 0.f) + fmaxf(m1.y + (float)hq1.a[1], 0.f);
        acc.z += fmaxf(m0.z + (float)hq0.b[0], 0.f) + fmaxf(m1.z + (float)hq1.b[0], 0.f);
        acc.w += fmaxf(m0.w + (float)hq0.b[1], 0.f) + fmaxf(m1.w + (float)hq1.b[1], 0.f);
        j += 2;
    }
    // ---- 1-wide remainder ----
    if (j < s1) {
        const int sn = perm_src[j];
        const EA8* pe = (const EA8*)(ea16 + (size_t)j * 16);
        const EA8 a0 = pe[0], c0 = pe[1];
        const HQ hq = *(const HQ*)(hin + (size_t)sn * DIN + fq * 4);
        const float4 m0 = eamlp2(a0, c0, ew2h, ebv);
        acc.x += fmaxf(m0.x + (float)hq.a[0], 0.f);
        acc.y += fmaxf(m0.y + (float)hq.a[1], 0.f);
        acc.z += fmaxf(m0.z + (float)hq.b[0], 0.f);
        acc.w += fmaxf(m0.w + (float)hq.b[1], 0.f);
    }

    // residual + f16 store: x = h_v + agg
    const HQ hv = *(const HQ*)(hin + (size_t)v * DIN + fq * 4);
    h4 o;
    o[0] = (_Float16)(acc.x + (float)hv.a[0]);
    o[1] = (_Float16)(acc.y + (float)hv.a[1]);
    o[2] = (_Float16)(acc.z + (float)hv.b[0]);
    o[3] = (_Float16)(acc.w + (float)hv.b[1]);
    *(h4*)(x16 + (size_t)v * DIN + fq * 4) = o;
}

// ---------------------------------------------------------------------------
// Node MLP: 1 wave per block, 1 16-node tile (round-4 verified structure).
// A-fragments for mm1 read DIRECTLY from global x16 (f16); s_t LDS only for
// the mm1->mm2 transpose. Always writes f16 h (pool reads f16 now).
// ---------------------------------------------------------------------------
template<int DIN>
__global__ __launch_bounds__(64) void node_mfma_kernel(
    const _Float16* __restrict__ x16,
    const _Float16* __restrict__ w1t, const float* __restrict__ b1,
    const float* __restrict__ gm, const float* __restrict__ bt,
    const _Float16* __restrict__ w2t, const float* __restrict__ b2,
    _Float16* __restrict__ h16out, int n_tiles)
{
    constexpr int STP = HID_C + 8;
    __shared__ _Float16 s_t[16][STP];

    const int lane = threadIdx.x;
    const int tile = blockIdx.x;
    const int node0 = tile * 16;
    const int ln   = lane & 15;
    const int quad = lane >> 4;

    // preload A-fragments of X (row ln, cols quad*8 + ks*32) from global
    constexpr int NKS = DIN / 32;
    h8 af[NKS];
#pragma unroll
    for (int ks = 0; ks < NKS; ++ks)
        af[ks] = *(const h8*)(x16 + (size_t)(node0 + ln) * DIN + ks * 32 + quad * 8);

    // ---- mm1 + BN + relu -> s_t (f16) ----
#pragma unroll
    for (int nt = 0; nt < 8; ++nt) {
        const int col = nt * 16 + ln;
        const float bv = b1[col];
        f4 acc = {bv, bv, bv, bv};
#pragma unroll
        for (int ks = 0; ks < NKS; ++ks) {
            const h8 bf = *(const h8*)(w1t + (size_t)col * DIN + ks * 32 + quad * 8);
            acc = __builtin_amdgcn_mfma_f32_16x16x32_f16(af[ks], bf, acc, 0, 0, 0);
        }
        const float gv = gm[col], btv = bt[col];
#pragma unroll
        for (int r = 0; r < 4; ++r) {
            const float t = fmaxf(fmaf(acc[r] * BN_SCALE_C, gv, btv), 0.f);
            s_t[quad * 4 + r][col] = (_Float16)t;
        }
    }
    __syncthreads();

    // preload A-fragments of T
    h8 af2[4];
#pragma unroll
    for (int ks = 0; ks < 4; ++ks)
        af2[ks] = *(const h8*)&s_t[ln][ks * 32 + quad * 8];

    // ---- mm2 + relu -> h16 ----
#pragma unroll
    for (int nt = 0; nt < 8; ++nt) {
        const int col = nt * 16 + ln;
        const float bv = b2[col];
        f4 acc = {bv, bv, bv, bv};
#pragma unroll
        for (int ks = 0; ks < 4; ++ks) {
            const h8 bf = *(const h8*)(w2t + (size_t)col * HID_C + ks * 32 + quad * 8);
            acc = __builtin_amdgcn_mfma_f32_16x16x32_f16(af2[ks], bf, acc, 0, 0, 0);
        }
#pragma unroll
        for (int r = 0; r < 4; ++r) {
            const int node = node0 + quad * 4 + r;
            h16out[(size_t)node * HID_C + col] = (_Float16)fmaxf(acc[r], 0.f);
        }
    }
}

// ---------------------------------------------------------------------------
// Pool + output MLP; reads the final f16 h (halves pool read traffic and
// removes the last layer's f32 mirror write).
// ---------------------------------------------------------------------------
__global__ __launch_bounds__(256) void pool_kernel(
    const _Float16* __restrict__ hfin, const int* __restrict__ batch,
    const float* __restrict__ w1, const float* __restrict__ b1,
    const float* __restrict__ w2, const float* __restrict__ b2,
    float* __restrict__ out, int n_nodes)
{
    const int gid = blockIdx.x;

    int lo = 0, hi = n_nodes;
    while (lo < hi) { int mid = (lo + hi) >> 1; if (batch[mid] < gid) lo = mid + 1; else hi = mid; }
    const int start = lo;
    hi = n_nodes;
    while (lo < hi) { int mid = (lo + hi) >> 1; if (batch[mid] < gid + 1) lo = mid + 1; else hi = mid; }
    const int end = lo;

    const int f = threadIdx.x & (HID_C - 1);
    const int half = threadIdx.x >> 7;

    float sum = 0.f;
    for (int n = start + half; n < end; n += 2)
        sum += (float)hfin[(size_t)n * HID_C + f];

    __shared__ float s_sum[2][HID_C];
    __shared__ float s_p[HID_C];
    __shared__ float s_t[HID_C];
    s_sum[half][f] = sum;
    __syncthreads();

    if (threadIdx.x < HID_C) {
        const float cnt = (float)(end - start);
        s_p[f] = (s_sum[0][f] + s_sum[1][f]) / fmaxf(cnt, 1.f);
    }
    __syncthreads();

    if (threadIdx.x < HID_C) {
        float acc = b1[f];
        for (int k = 0; k < HID_C; ++k) acc = fmaf(s_p[k], w1[k * HID_C + f], acc);
        s_t[f] = fmaxf(acc, 0.f);
    }
    __syncthreads();

    if (threadIdx.x < HID_C) {
        float acc = b2[f];
        for (int k = 0; k < HID_C; ++k) acc = fmaf(s_t[k], w2[k * HID_C + f], acc);
        out[(size_t)gid * HID_C + f] = acc;
    }
}

// ---------------------------------------------------------------------------
extern "C" void kernel_launch(void* const* d_in, const int* in_sizes, int n_in,
                              void* d_out, int out_size, void* d_ws, size_t ws_size,
                              hipStream_t stream)
{
    const float* x         = (const float*)d_in[0];
    const float* edge_attr = (const float*)d_in[1];
    const int*   edge_index= (const int*)  d_in[2];
    const int*   batch     = (const int*)  d_in[3];
    const int*   src = edge_index;
    const int*   dst = edge_index + N_EDGES_C;

    const float* el_w[3] = {(const float*)d_in[4],  (const float*)d_in[12], (const float*)d_in[20]};
    const float* el_b[3] = {(const float*)d_in[5],  (const float*)d_in[13], (const float*)d_in[21]};
    const float* c_w1[3] = {(const float*)d_in[6],  (const float*)d_in[14], (const float*)d_in[22]};
    const float* c_b1[3] = {(const float*)d_in[7],  (const float*)d_in[15], (const float*)d_in[23]};
    const float* c_g [3] = {(const float*)d_in[8],  (const float*)d_in[16], (const float*)d_in[24]};
    const float* c_bt[3] = {(const float*)d_in[9],  (const float*)d_in[17], (const float*)d_in[25]};
    const float* c_w2[3] = {(const float*)d_in[10], (const float*)d_in[18], (const float*)d_in[26]};
    const float* c_b2[3] = {(const float*)d_in[11], (const float*)d_in[19], (const float*)d_in[27]};
    const float* o_w1 = (const float*)d_in[28];
    const float* o_b1 = (const float*)d_in[29];
    const float* o_w2 = (const float*)d_in[30];
    const float* o_b2 = (const float*)d_in[31];

    // ---- workspace layout (~150 MB) ----
    char* wsp = (char*)d_ws;
    size_t used = 0;
    auto alloc = [&](size_t bytes) { char* p = wsp + used; used += (bytes + 255) & ~(size_t)255; return p; };
    int*   counts   = (int*)alloc((size_t)N_NODES_C * 4);
    int*   incl     = (int*)alloc((size_t)N_NODES_C * 4);
    int*   rowstart = (int*)alloc((size_t)N_NODES_C * 4);
    int*   cursor   = (int*)alloc((size_t)N_NODES_C * 4);
    int*   blocksums= (int*)alloc(128 * 4);
    int*   blockoffs= (int*)alloc(128 * 4);
    int*   perm_src = (int*)alloc((size_t)N_EDGES_C * 4);
    _Float16* ea_f16 = (_Float16*)alloc((size_t)N_EDGES_C * 16 * 2);
    _Float16* x16    = (_Float16*)alloc((size_t)N_NODES_C * HID_C * 2);
    _Float16* h16_a  = (_Float16*)alloc((size_t)N_NODES_C * HID_C * 2);
    _Float16* h16_b  = (_Float16*)alloc((size_t)N_NODES_C * HID_C * 2);
    _Float16* x_f16  = (_Float16*)alloc((size_t)N_NODES_C * 64 * 2);
    _Float16* w1t[3], *w2t[3];
    for (int l = 0; l < 3; ++l) {
        w1t[l] = (_Float16*)alloc((size_t)HID_C * HID_C * 2);
        w2t[l] = (_Float16*)alloc((size_t)HID_C * HID_C * 2);
    }
    (void)ws_size;

    // ---- CSR build (once; reused by all 3 layers) ----
    hipMemsetAsync(counts, 0, (size_t)N_NODES_C * 4, stream);
    hist_kernel<<<(N_EDGES_C + 255) / 256, 256, 0, stream>>>(dst, counts, N_EDGES_C);
    scan1_kernel<<<SCAN_NB, SCAN_B, 0, stream>>>(counts, incl, blocksums, N_NODES_C);
    scan2_kernel<<<1, 64, 0, stream>>>(blocksums, blockoffs, SCAN_NB);
    scan3_kernel<<<SCAN_NB, SCAN_B, 0, stream>>>(incl, blockoffs, N_NODES_C);
    initrows_kernel<<<(N_NODES_C + 255) / 256, 256, 0, stream>>>(incl, counts, rowstart,
                                                                 cursor, N_NODES_C);
    scatter_ea_kernel<<<(N_EDGES_C + 255) / 256, 256, 0, stream>>>(
        src, dst, cursor, perm_src, edge_attr, (__half*)ea_f16, N_EDGES_C);
    cast_f16_kernel<<<(N_NODES_C * 64 / 4 + 255) / 256, 256, 0, stream>>>(
        x, x_f16, N_NODES_C * 64 / 4);
    for (int l = 0; l < 3; ++l) {
        const int K1 = (l == 0) ? 64 : HID_C;
        transpose_w_kernel<<<(K1 * HID_C + 255) / 256, 256, 0, stream>>>(
            c_w1[l], w1t[l], K1, HID_C);
        transpose_w_kernel<<<(HID_C * HID_C + 255) / 256, 256, 0, stream>>>(
            c_w2[l], w2t[l], HID_C, HID_C);
    }

    const int n_tiles = N_NODES_C / 16;            // 6250

    // ---- 3 GINE layers (split: high-TLP agg -> tiny MFMA node MLP) ----
    // layer 0 (DIN=64)
    gine_agg_kernel<64><<<(N_NODES_C + 15) / 16, 256, 0, stream>>>(
        x_f16, ea_f16, perm_src, rowstart, incl, el_w[0], el_b[0],
        x16, N_NODES_C);
    node_mfma_kernel<64><<<n_tiles, 64, 0, stream>>>(
        x16, w1t[0], c_b1[0], c_g[0], c_bt[0], w2t[0], c_b2[0],
        h16_a, n_tiles);
    // layer 1
    gine_agg_kernel<128><<<(N_NODES_C + 7) / 8, 256, 0, stream>>>(
        h16_a, ea_f16, perm_src, rowstart, incl, el_w[1], el_b[1],
        x16, N_NODES_C);
    node_mfma_kernel<128><<<n_tiles, 64, 0, stream>>>(
        x16, w1t[1], c_b1[1], c_g[1], c_bt[1], w2t[1], c_b2[1],
        h16_b, n_tiles);
    // layer 2
    gine_agg_kernel<128><<<(N_NODES_C + 7) / 8, 256, 0, stream>>>(
        h16_b, ea_f16, perm_src, rowstart, incl, el_w[2], el_b[2],
        x16, N_NODES_C);
    node_mfma_kernel<128><<<n_tiles, 64, 0, stream>>>(
        x16, w1t[2], c_b1[2], c_g[2], c_bt[2], w2t[2], c_b2[2],
        h16_a, n_tiles);

    // ---- pool + output MLP (reads f16) ----
    pool_kernel<<<N_GRAPHS_C, 256, 0, stream>>>(h16_a, batch, o_w1, o_b1, o_w2, o_b2,
                                                (float*)d_out, N_NODES_C);
}